// Round 3
// baseline (316.883 us; speedup 1.0000x reference)
//
#include <hip/hip_runtime.h>

// ---------- types & helpers ----------
typedef unsigned short u16;
typedef float f32x4 __attribute__((ext_vector_type(4)));
typedef short s16x8 __attribute__((ext_vector_type(8)));
typedef unsigned short u16x4 __attribute__((ext_vector_type(4)));

__device__ __forceinline__ u16 f2bf(float f) {
  union { float f; unsigned u; } v; v.f = f;
  unsigned r = v.u + 0x7FFFu + ((v.u >> 16) & 1u);   // RNE
  return (u16)(r >> 16);
}

__device__ __forceinline__ void gload_lds16(const void* g, void* l) {
  __builtin_amdgcn_global_load_lds(
      (const __attribute__((address_space(1))) void*)g,
      (__attribute__((address_space(3))) void*)l, 16, 0, 0);
}

// ---------- fp32 -> bf16 cast ----------
__global__ __launch_bounds__(256) void cast_f32_bf16(
    const float* __restrict__ src, u16* __restrict__ dst, int n4) {
  int i = blockIdx.x * 256 + threadIdx.x;
  if (i >= n4) return;
  f32x4 v = ((const f32x4*)src)[i];
  u16x4 o = { f2bf(v[0]), f2bf(v[1]), f2bf(v[2]), f2bf(v[3]) };
  ((u16x4*)dst)[i] = o;
}

// ---------- bt-GEMM: C[M,N] = A[M,K] * B[N,K]^T  (bf16 in, fp32 acc) ----------
// 128x128 tile, BK=32, 256 threads (4 waves in 2x2), m97 structure.
// FINAL=0: bf16 C, no bias.  FINAL=1: fp32 C + bias[col].
template <int FINAL>
__global__ __launch_bounds__(256) void gemm_bt(
    const u16* __restrict__ A, const u16* __restrict__ B,
    void* __restrict__ Cout, const float* __restrict__ bias,
    int K, int lda, int ldb, int ldc) {
  __shared__ u16 As[128 * 32];
  __shared__ u16 Bs[128 * 32];
  const int tid = threadIdx.x;
  const int wid = tid >> 6, lane = tid & 63;
  const int lo = lane & 15, hi = lane >> 4;
  const int wr = wid >> 1, wc = wid & 1;
  const long brow = (long)blockIdx.y * 128;
  const long bcol = (long)blockIdx.x * 128;

  f32x4 acc[4][4] = {};

  const char* Ab = (const char*)(A + (size_t)brow * lda);
  const char* Bb = (const char*)(B + (size_t)bcol * ldb);
  const int ldab = lda * 2, ldbb = ldb * 2;

  for (int k0 = 0; k0 < K; k0 += 32) {
#pragma unroll
    for (int i = 0; i < 2; ++i) {
      int ob = wid * 2048 + i * 1024;    // wave-uniform LDS base
      int o = ob + lane * 16;
      int row = o >> 6, cb = o & 63;
      gload_lds16(Ab + (size_t)row * ldab + k0 * 2 + cb, (char*)As + ob);
      gload_lds16(Bb + (size_t)row * ldbb + k0 * 2 + cb, (char*)Bs + ob);
    }
    __syncthreads();   // drains vmcnt(0) then barrier
    s16x8 af[4], bfr[4];
#pragma unroll
    for (int m = 0; m < 4; ++m)
      af[m] = *(const s16x8*)&As[(wr * 64 + m * 16 + lo) * 32 + hi * 8];
#pragma unroll
    for (int n = 0; n < 4; ++n)
      bfr[n] = *(const s16x8*)&Bs[(wc * 64 + n * 16 + lo) * 32 + hi * 8];
#pragma unroll
    for (int m = 0; m < 4; ++m)
#pragma unroll
      for (int n = 0; n < 4; ++n)
        acc[m][n] = __builtin_amdgcn_mfma_f32_16x16x32_bf16(af[m], bfr[n], acc[m][n], 0, 0, 0);
    __syncthreads();
  }
#pragma unroll
  for (int m = 0; m < 4; ++m) {
#pragma unroll
    for (int n = 0; n < 4; ++n) {
#pragma unroll
      for (int r = 0; r < 4; ++r) {
        size_t row = brow + wr * 64 + m * 16 + hi * 4 + r;
        size_t col = bcol + wc * 64 + n * 16 + lo;
        float v = acc[m][n][r];
        if (FINAL) ((float*)Cout)[row * ldc + col] = v + bias[col];
        else       ((u16*)Cout)[row * ldc + col] = f2bf(v);
      }
    }
  }
}

// ---------- Ke/Vf: per (kc, b*h, type) block computes 64k x 64d ----------
// KeT[bh][k][d] = sum_n We[h][k][n]*K[bh][n][d] + bE   (type 0)
// Vf [bh][d][k] = sum_n Wf[h][k][n]*V[bh][n][d] + bF   (type 1)
__global__ __launch_bounds__(256) void kevf_kernel(
    const float* __restrict__ We, const float* __restrict__ bE,
    const float* __restrict__ Wf, const float* __restrict__ bF,
    const u16* __restrict__ QKV, u16* __restrict__ KeT, u16* __restrict__ Vf) {
  __shared__ u16 Wa[64 * 32];   // [kk][n] bf16, xor-swizzled 16B slots
  __shared__ u16 Vt[64 * 32];   // [dd][n] bf16, n xor-swizzled by dd
  const int type = blockIdx.z;
  const int bh = blockIdx.y, b = bh >> 4, h = bh & 15;
  const int kk0 = blockIdx.x * 64;
  const float* W = (type ? Wf : We) + ((size_t)(h * 256 + kk0)) * 4096;
  const float* bias = (type ? bF : bE) + h * 256 + kk0;
  const int col0 = (type ? 2048 : 1024) + h * 64;
  const int tid = threadIdx.x, wid = tid >> 6, lane = tid & 63;
  const int lo = lane & 15, hi = lane >> 4;

  f32x4 acc[4] = {};

  for (int n0 = 0; n0 < 4096; n0 += 32) {
    { // stage W (fp32 -> bf16)
      int r = tid >> 2, c8 = (tid & 3) * 8;
      const f32x4* wp = (const f32x4*)(W + (size_t)r * 4096 + n0 + c8);
      f32x4 v0 = wp[0], v1 = wp[1];
      s16x8 wv;
      wv[0] = (short)f2bf(v0[0]); wv[1] = (short)f2bf(v0[1]);
      wv[2] = (short)f2bf(v0[2]); wv[3] = (short)f2bf(v0[3]);
      wv[4] = (short)f2bf(v1[0]); wv[5] = (short)f2bf(v1[1]);
      wv[6] = (short)f2bf(v1[2]); wv[7] = (short)f2bf(v1[3]);
      *(s16x8*)((char*)Wa + r * 64 + ((c8 * 2) ^ ((r & 3) << 4))) = wv;
    }
    { // stage V/K transposed
      int n = tid >> 3, dd0 = (tid & 7) * 8;
      s16x8 v = *(const s16x8*)(QKV + (size_t)(b * 4096 + n0 + n) * 3072 + col0 + dd0);
#pragma unroll
      for (int q = 0; q < 8; ++q) {
        int dd = dd0 + q;
        Vt[dd * 32 + (n ^ (((dd >> 3) & 3) << 3))] = (u16)v[q];
      }
    }
    __syncthreads();
    int rr = wid * 16 + lo;
    s16x8 a = *(const s16x8*)((const char*)Wa + rr * 64 + ((hi * 16) ^ ((rr & 3) << 4)));
#pragma unroll
    for (int dt = 0; dt < 4; ++dt) {
      int dd = dt * 16 + lo;
      s16x8 bv = *(const s16x8*)&Vt[dd * 32 + ((hi * 8) ^ (((dd >> 3) & 3) << 3))];
      acc[dt] = __builtin_amdgcn_mfma_f32_16x16x32_bf16(a, bv, acc[dt], 0, 0, 0);
    }
    __syncthreads();
  }
#pragma unroll
  for (int dt = 0; dt < 4; ++dt) {
#pragma unroll
    for (int r = 0; r < 4; ++r) {
      int kkl = wid * 16 + hi * 4 + r;
      int dd = dt * 16 + lo;
      float v = acc[dt][r] + bias[kkl];
      if (type == 0) KeT[((size_t)bh * 256 + kk0 + kkl) * 64 + dd] = f2bf(v);
      else           Vf[((size_t)bh * 64 + dd) * 256 + kk0 + kkl] = f2bf(v);
    }
  }
}

// ---------- fused attention: scores -> softmax -> PV -> gelu ----------
// grid (64 ntiles, 32 bh); 256 threads = 4 waves x 16 q-rows each.
__global__ __launch_bounds__(256) void attn_fused(
    const u16* __restrict__ QKV, const u16* __restrict__ KeT,
    const u16* __restrict__ Vf, u16* __restrict__ attn) {
  __shared__ char smem[65536];
  char* sKe = smem;           // [256][128B] swizzled (aliased by P later)
  char* sVf = smem + 32768;   // [64][512B] swizzled
  const int tid = threadIdx.x, wid = tid >> 6, lane = tid & 63;
  const int lo = lane & 15, hi = lane >> 4;
  const int bh = blockIdx.y, b = bh >> 4, h = bh & 15;
  const int n0 = blockIdx.x * 64;

  const char* keg = (const char*)(KeT + (size_t)bh * 256 * 64);
  const char* vfg = (const char*)(Vf + (size_t)bh * 64 * 256);
#pragma unroll
  for (int i = 0; i < 8; ++i) {
    int ob = wid * 8192 + i * 1024;
    int o = ob + lane * 16;
    int kr = o >> 7, kc = o & 127;
    gload_lds16(keg + kr * 128 + (kc ^ ((kr & 7) << 4)), sKe + ob);
    int vr = o >> 9, vc = o & 511;
    gload_lds16(vfg + vr * 512 + (vc ^ ((vr & 7) << 4)), sVf + ob);
  }
  const u16* qp = QKV + (size_t)(b * 4096 + n0 + wid * 16 + lo) * 3072 + h * 64;
  s16x8 qf0 = *(const s16x8*)(qp + hi * 8);
  s16x8 qf1 = *(const s16x8*)(qp + 32 + hi * 8);
  __syncthreads();

  f32x4 sc[16];
#pragma unroll
  for (int nt = 0; nt < 16; ++nt) {
    int kk = nt * 16 + lo;
    int sw = (kk & 7) << 4;
    s16x8 b0 = *(const s16x8*)(sKe + kk * 128 + ((hi * 16) ^ sw));
    s16x8 b1 = *(const s16x8*)(sKe + kk * 128 + ((64 + hi * 16) ^ sw));
    f32x4 c = {0.f, 0.f, 0.f, 0.f};
    c = __builtin_amdgcn_mfma_f32_16x16x32_bf16(qf0, b0, c, 0, 0, 0);
    c = __builtin_amdgcn_mfma_f32_16x16x32_bf16(qf1, b1, c, 0, 0, 0);
    sc[nt] = c;
  }
  // softmax over 256 (rows live on 16-lane groups: row = hi*4+r, col = nt*16+lo)
  float mx[4], inv[4];
#pragma unroll
  for (int r = 0; r < 4; ++r) {
    float m = sc[0][r];
#pragma unroll
    for (int nt = 1; nt < 16; ++nt) m = fmaxf(m, sc[nt][r]);
    m = fmaxf(m, __shfl_xor(m, 1));
    m = fmaxf(m, __shfl_xor(m, 2));
    m = fmaxf(m, __shfl_xor(m, 4));
    m = fmaxf(m, __shfl_xor(m, 8));
    mx[r] = m;
  }
  const float SCL = 0.125f * 1.4426950408889634f;   // (1/sqrt(64)) * log2(e)
  float sm[4] = {0.f, 0.f, 0.f, 0.f};
#pragma unroll
  for (int nt = 0; nt < 16; ++nt)
#pragma unroll
    for (int r = 0; r < 4; ++r) {
      float p = exp2f((sc[nt][r] - mx[r]) * SCL);
      sc[nt][r] = p;
      sm[r] += p;
    }
#pragma unroll
  for (int r = 0; r < 4; ++r) {
    float s = sm[r];
    s += __shfl_xor(s, 1);
    s += __shfl_xor(s, 2);
    s += __shfl_xor(s, 4);
    s += __shfl_xor(s, 8);
    inv[r] = 1.0f / s;
  }
  __syncthreads();            // all waves done reading sKe
  char* pb = smem + wid * 8192;  // P aliases sKe region: [16 rows][512B] per wave
#pragma unroll
  for (int nt = 0; nt < 16; ++nt)
#pragma unroll
    for (int r = 0; r < 4; ++r) {
      int row = hi * 4 + r;
      int kk = nt * 16 + lo;
      *(u16*)(pb + row * 512 + ((kk * 2) ^ ((row & 7) << 4))) = f2bf(sc[nt][r] * inv[r]);
    }
  __syncthreads();
  s16x8 pa[8];
#pragma unroll
  for (int ks = 0; ks < 8; ++ks)
    pa[ks] = *(const s16x8*)(pb + lo * 512 + ((ks * 64 + hi * 16) ^ ((lo & 7) << 4)));
#pragma unroll
  for (int dt = 0; dt < 4; ++dt) {
    int dd = dt * 16 + lo;
    int sw = (dd & 7) << 4;
    f32x4 o = {0.f, 0.f, 0.f, 0.f};
#pragma unroll
    for (int ks = 0; ks < 8; ++ks) {
      s16x8 vb = *(const s16x8*)(sVf + dd * 512 + ((ks * 64 + hi * 16) ^ sw));
      o = __builtin_amdgcn_mfma_f32_16x16x32_bf16(pa[ks], vb, o, 0, 0, 0);
    }
#pragma unroll
    for (int r = 0; r < 4; ++r) {
      int row = n0 + wid * 16 + hi * 4 + r;
      float x = o[r];
      float g = 0.5f * x * (1.0f + erff(x * 0.7071067811865476f));
      attn[(size_t)(b * 4096 + row) * 1024 + h * 64 + dd] = f2bf(g);
    }
  }
}

// ---------- launcher ----------
extern "C" void kernel_launch(void* const* d_in, const int* in_sizes, int n_in,
                              void* d_out, int out_size, void* d_ws, size_t ws_size,
                              hipStream_t stream) {
  const float* x  = (const float*)d_in[0];
  const float* Wq = (const float*)d_in[1];
  const float* Wk = (const float*)d_in[2];
  const float* Wv = (const float*)d_in[3];
  const float* We = (const float*)d_in[4];
  const float* bE = (const float*)d_in[5];
  const float* Wf = (const float*)d_in[6];
  const float* bF = (const float*)d_in[7];
  const float* Wo = (const float*)d_in[8];
  const float* bo = (const float*)d_in[9];
  float* out = (float*)d_out;

  char* ws = (char*)d_ws;
  u16* xb   = (u16*)(ws);                 // 16,777,216 B  [8192][1024] bf16
  u16* Wqkv = (u16*)(ws + 16777216);      //  6,291,456 B  [3072][1024] bf16
  u16* Wob  = (u16*)(ws + 23068672);      //  2,097,152 B  [1024][1024] bf16
  u16* QKV  = (u16*)(ws + 25165824);      // 50,331,648 B  [8192][3072] bf16
  u16* KeT  = (u16*)(ws + 75497472);      //  1,048,576 B  [32][256][64] bf16
  u16* Vf   = (u16*)(ws + 76546048);      //  1,048,576 B  [32][64][256] bf16
  u16* attn = (u16*)(ws + 77594624);      // 16,777,216 B  [8192][1024] bf16

  cast_f32_bf16<<<8192, 256, 0, stream>>>(x, xb, 2097152);
  cast_f32_bf16<<<1024, 256, 0, stream>>>(Wq, Wqkv, 262144);
  cast_f32_bf16<<<1024, 256, 0, stream>>>(Wk, Wqkv + 1048576, 262144);
  cast_f32_bf16<<<1024, 256, 0, stream>>>(Wv, Wqkv + 2097152, 262144);
  cast_f32_bf16<<<1024, 256, 0, stream>>>(Wo, Wob, 262144);

  // QKV projection: [8192,3072] = x[8192,1024] @ Wqkv[3072,1024]^T
  gemm_bt<0><<<dim3(24, 64), 256, 0, stream>>>(xb, Wqkv, QKV, nullptr,
                                               1024, 1024, 1024, 3072);
  // Ke/Vf low-rank projections
  kevf_kernel<<<dim3(4, 32, 2), 256, 0, stream>>>(We, bE, Wf, bF, QKV, KeT, Vf);
  // fused scores/softmax/PV/gelu
  attn_fused<<<dim3(64, 32), 256, 0, stream>>>(QKV, KeT, Vf, attn);
  // output projection + bias
  gemm_bt<1><<<dim3(8, 64), 256, 0, stream>>>(attn, Wob, out, bo,
                                              1024, 1024, 1024, 1024);
}

// Round 4
// 315.614 us; speedup vs baseline: 1.0040x; 1.0040x over previous
//
#include <hip/hip_runtime.h>

// ---------- types & helpers ----------
typedef unsigned short u16;
typedef float f32x4 __attribute__((ext_vector_type(4)));
typedef short s16x8 __attribute__((ext_vector_type(8)));
typedef unsigned short u16x4 __attribute__((ext_vector_type(4)));

__device__ __forceinline__ u16 f2bf(float f) {
  union { float f; unsigned u; } v; v.f = f;
  unsigned r = v.u + 0x7FFFu + ((v.u >> 16) & 1u);   // RNE
  return (u16)(r >> 16);
}

__device__ __forceinline__ void gload_lds16(const void* g, void* l) {
  __builtin_amdgcn_global_load_lds(
      (const __attribute__((address_space(1))) void*)g,
      (__attribute__((address_space(3))) void*)l, 16, 0, 0);
}

// ---------- fp32 -> bf16 cast ----------
__global__ __launch_bounds__(256) void cast_f32_bf16(
    const float* __restrict__ src, u16* __restrict__ dst, int n4) {
  int i = blockIdx.x * 256 + threadIdx.x;
  if (i >= n4) return;
  f32x4 v = ((const f32x4*)src)[i];
  u16x4 o = { f2bf(v[0]), f2bf(v[1]), f2bf(v[2]), f2bf(v[3]) };
  ((u16x4*)dst)[i] = o;
}

// ---------- bt-GEMM: C[M,N] = A[M,K] * B[N,K]^T  (bf16 in, fp32 acc) ----------
// 128x128 tile, BK=32, 256 threads (4 waves in 2x2), m97 structure.
// FINAL=0: bf16 C, no bias.  FINAL=1: fp32 C + bias[col].
template <int FINAL>
__global__ __launch_bounds__(256) void gemm_bt(
    const u16* __restrict__ A, const u16* __restrict__ B,
    void* __restrict__ Cout, const float* __restrict__ bias,
    int K, int lda, int ldb, int ldc) {
  __shared__ u16 As[128 * 32];
  __shared__ u16 Bs[128 * 32];
  const int tid = threadIdx.x;
  const int wid = tid >> 6, lane = tid & 63;
  const int lo = lane & 15, hi = lane >> 4;
  const int wr = wid >> 1, wc = wid & 1;
  const long brow = (long)blockIdx.y * 128;
  const long bcol = (long)blockIdx.x * 128;

  f32x4 acc[4][4] = {};

  const char* Ab = (const char*)(A + (size_t)brow * lda);
  const char* Bb = (const char*)(B + (size_t)bcol * ldb);
  const int ldab = lda * 2, ldbb = ldb * 2;

  for (int k0 = 0; k0 < K; k0 += 32) {
#pragma unroll
    for (int i = 0; i < 2; ++i) {
      int ob = wid * 2048 + i * 1024;    // wave-uniform LDS base
      int o = ob + lane * 16;
      int row = o >> 6, cb = o & 63;
      gload_lds16(Ab + (size_t)row * ldab + k0 * 2 + cb, (char*)As + ob);
      gload_lds16(Bb + (size_t)row * ldbb + k0 * 2 + cb, (char*)Bs + ob);
    }
    __syncthreads();   // drains vmcnt(0) then barrier
    s16x8 af[4], bfr[4];
#pragma unroll
    for (int m = 0; m < 4; ++m)
      af[m] = *(const s16x8*)&As[(wr * 64 + m * 16 + lo) * 32 + hi * 8];
#pragma unroll
    for (int n = 0; n < 4; ++n)
      bfr[n] = *(const s16x8*)&Bs[(wc * 64 + n * 16 + lo) * 32 + hi * 8];
#pragma unroll
    for (int m = 0; m < 4; ++m)
#pragma unroll
      for (int n = 0; n < 4; ++n)
        acc[m][n] = __builtin_amdgcn_mfma_f32_16x16x32_bf16(af[m], bfr[n], acc[m][n], 0, 0, 0);
    __syncthreads();
  }
#pragma unroll
  for (int m = 0; m < 4; ++m) {
#pragma unroll
    for (int n = 0; n < 4; ++n) {
#pragma unroll
      for (int r = 0; r < 4; ++r) {
        size_t row = brow + wr * 64 + m * 16 + hi * 4 + r;
        size_t col = bcol + wc * 64 + n * 16 + lo;
        float v = acc[m][n][r];
        if (FINAL) ((float*)Cout)[row * ldc + col] = v + bias[col];
        else       ((u16*)Cout)[row * ldc + col] = f2bf(v);
      }
    }
  }
}

// ---------- Ke/Vf: per (kc, b*h, type) block computes 64k x 64d ----------
// KeT[bh][k][d] = sum_n We[h][k][n]*K[bh][n][d] + bE   (type 0)
// Vf [bh][d][k] = sum_n Wf[h][k][n]*V[bh][n][d] + bF   (type 1)
__global__ __launch_bounds__(256) void kevf_kernel(
    const float* __restrict__ We, const float* __restrict__ bE,
    const float* __restrict__ Wf, const float* __restrict__ bF,
    const u16* __restrict__ QKV, u16* __restrict__ KeT, u16* __restrict__ Vf) {
  __shared__ u16 Wa[64 * 32];   // [kk][n] bf16, xor-swizzled 16B slots
  __shared__ u16 Vt[64 * 32];   // [dd][n] bf16, n xor-swizzled by dd
  const int type = blockIdx.z;
  const int bh = blockIdx.y, b = bh >> 4, h = bh & 15;
  const int kk0 = blockIdx.x * 64;
  const float* W = (type ? Wf : We) + ((size_t)(h * 256 + kk0)) * 4096;
  const float* bias = (type ? bF : bE) + h * 256 + kk0;
  const int col0 = (type ? 2048 : 1024) + h * 64;
  const int tid = threadIdx.x, wid = tid >> 6, lane = tid & 63;
  const int lo = lane & 15, hi = lane >> 4;

  f32x4 acc[4] = {};

  for (int n0 = 0; n0 < 4096; n0 += 32) {
    { // stage W (fp32 -> bf16)
      int r = tid >> 2, c8 = (tid & 3) * 8;
      const f32x4* wp = (const f32x4*)(W + (size_t)r * 4096 + n0 + c8);
      f32x4 v0 = wp[0], v1 = wp[1];
      s16x8 wv;
      wv[0] = (short)f2bf(v0[0]); wv[1] = (short)f2bf(v0[1]);
      wv[2] = (short)f2bf(v0[2]); wv[3] = (short)f2bf(v0[3]);
      wv[4] = (short)f2bf(v1[0]); wv[5] = (short)f2bf(v1[1]);
      wv[6] = (short)f2bf(v1[2]); wv[7] = (short)f2bf(v1[3]);
      *(s16x8*)((char*)Wa + r * 64 + ((c8 * 2) ^ ((r & 3) << 4))) = wv;
    }
    { // stage V/K transposed
      int n = tid >> 3, dd0 = (tid & 7) * 8;
      s16x8 v = *(const s16x8*)(QKV + (size_t)(b * 4096 + n0 + n) * 3072 + col0 + dd0);
#pragma unroll
      for (int q = 0; q < 8; ++q) {
        int dd = dd0 + q;
        Vt[dd * 32 + (n ^ (((dd >> 3) & 3) << 3))] = (u16)v[q];
      }
    }
    __syncthreads();
    int rr = wid * 16 + lo;
    s16x8 a = *(const s16x8*)((const char*)Wa + rr * 64 + ((hi * 16) ^ ((rr & 3) << 4)));
#pragma unroll
    for (int dt = 0; dt < 4; ++dt) {
      int dd = dt * 16 + lo;
      s16x8 bv = *(const s16x8*)&Vt[dd * 32 + ((hi * 8) ^ (((dd >> 3) & 3) << 3))];
      acc[dt] = __builtin_amdgcn_mfma_f32_16x16x32_bf16(a, bv, acc[dt], 0, 0, 0);
    }
    __syncthreads();
  }
#pragma unroll
  for (int dt = 0; dt < 4; ++dt) {
#pragma unroll
    for (int r = 0; r < 4; ++r) {
      int kkl = wid * 16 + hi * 4 + r;
      int dd = dt * 16 + lo;
      float v = acc[dt][r] + bias[kkl];
      if (type == 0) KeT[((size_t)bh * 256 + kk0 + kkl) * 64 + dd] = f2bf(v);
      else           Vf[((size_t)bh * 64 + dd) * 256 + kk0 + kkl] = f2bf(v);
    }
  }
}

// ---------- fused attention: scores -> softmax -> PV -> gelu ----------
// grid (64 ntiles, 32 bh); 256 threads = 4 waves x 16 q-rows each.
__global__ __launch_bounds__(256) void attn_fused(
    const u16* __restrict__ QKV, const u16* __restrict__ KeT,
    const u16* __restrict__ Vf, u16* __restrict__ attn) {
  __shared__ char smem[65536];
  char* sKe = smem;           // [256][128B] swizzled (aliased by P later)
  char* sVf = smem + 32768;   // [64][512B] swizzled
  const int tid = threadIdx.x, wid = tid >> 6, lane = tid & 63;
  const int lo = lane & 15, hi = lane >> 4;
  const int bh = blockIdx.y, b = bh >> 4, h = bh & 15;
  const int n0 = blockIdx.x * 64;

  const char* keg = (const char*)(KeT + (size_t)bh * 256 * 64);
  const char* vfg = (const char*)(Vf + (size_t)bh * 64 * 256);
#pragma unroll
  for (int i = 0; i < 8; ++i) {
    int ob = wid * 8192 + i * 1024;
    int o = ob + lane * 16;
    int kr = o >> 7, kc = o & 127;
    gload_lds16(keg + kr * 128 + (kc ^ ((kr & 7) << 4)), sKe + ob);
    int vr = o >> 9, vc = o & 511;
    gload_lds16(vfg + vr * 512 + (vc ^ ((vr & 7) << 4)), sVf + ob);
  }
  const u16* qp = QKV + (size_t)(b * 4096 + n0 + wid * 16 + lo) * 3072 + h * 64;
  s16x8 qf0 = *(const s16x8*)(qp + hi * 8);
  s16x8 qf1 = *(const s16x8*)(qp + 32 + hi * 8);
  __syncthreads();

  f32x4 sc[16];
#pragma unroll
  for (int nt = 0; nt < 16; ++nt) {
    int kk = nt * 16 + lo;
    int sw = (kk & 7) << 4;
    s16x8 b0 = *(const s16x8*)(sKe + kk * 128 + ((hi * 16) ^ sw));
    s16x8 b1 = *(const s16x8*)(sKe + kk * 128 + ((64 + hi * 16) ^ sw));
    f32x4 c = {0.f, 0.f, 0.f, 0.f};
    c = __builtin_amdgcn_mfma_f32_16x16x32_bf16(qf0, b0, c, 0, 0, 0);
    c = __builtin_amdgcn_mfma_f32_16x16x32_bf16(qf1, b1, c, 0, 0, 0);
    sc[nt] = c;
  }
  // softmax over 256 (rows live on 16-lane groups: row = hi*4+r, col = nt*16+lo)
  float mx[4], inv[4];
#pragma unroll
  for (int r = 0; r < 4; ++r) {
    float m = sc[0][r];
#pragma unroll
    for (int nt = 1; nt < 16; ++nt) m = fmaxf(m, sc[nt][r]);
    m = fmaxf(m, __shfl_xor(m, 1));
    m = fmaxf(m, __shfl_xor(m, 2));
    m = fmaxf(m, __shfl_xor(m, 4));
    m = fmaxf(m, __shfl_xor(m, 8));
    mx[r] = m;
  }
  const float SCL = 0.125f * 1.4426950408889634f;   // (1/sqrt(64)) * log2(e)
  float sm[4] = {0.f, 0.f, 0.f, 0.f};
#pragma unroll
  for (int nt = 0; nt < 16; ++nt)
#pragma unroll
    for (int r = 0; r < 4; ++r) {
      float p = exp2f((sc[nt][r] - mx[r]) * SCL);
      sc[nt][r] = p;
      sm[r] += p;
    }
#pragma unroll
  for (int r = 0; r < 4; ++r) {
    float s = sm[r];
    s += __shfl_xor(s, 1);
    s += __shfl_xor(s, 2);
    s += __shfl_xor(s, 4);
    s += __shfl_xor(s, 8);
    inv[r] = 1.0f / s;
  }
  __syncthreads();            // all waves done reading sKe
  char* pb = smem + wid * 8192;  // P aliases sKe region: [16 rows][512B] per wave
#pragma unroll
  for (int nt = 0; nt < 16; ++nt)
#pragma unroll
    for (int r = 0; r < 4; ++r) {
      int row = hi * 4 + r;
      int kk = nt * 16 + lo;
      *(u16*)(pb + row * 512 + ((kk * 2) ^ ((row & 7) << 4))) = f2bf(sc[nt][r] * inv[r]);
    }
  __syncthreads();
  s16x8 pa[8];
#pragma unroll
  for (int ks = 0; ks < 8; ++ks)
    pa[ks] = *(const s16x8*)(pb + lo * 512 + ((ks * 64 + hi * 16) ^ ((lo & 7) << 4)));
#pragma unroll
  for (int dt = 0; dt < 4; ++dt) {
    int dd = dt * 16 + lo;
    int sw = (dd & 7) << 4;
    f32x4 o = {0.f, 0.f, 0.f, 0.f};
#pragma unroll
    for (int ks = 0; ks < 8; ++ks) {
      s16x8 vb = *(const s16x8*)(sVf + dd * 512 + ((ks * 64 + hi * 16) ^ sw));
      o = __builtin_amdgcn_mfma_f32_16x16x32_bf16(pa[ks], vb, o, 0, 0, 0);
    }
#pragma unroll
    for (int r = 0; r < 4; ++r) {
      int row = n0 + wid * 16 + hi * 4 + r;
      float x = o[r];
      float g = 0.5f * x * (1.0f + erff(x * 0.7071067811865476f));
      attn[(size_t)(b * 4096 + row) * 1024 + h * 64 + dd] = f2bf(g);
    }
  }
}

// ---------- launcher ----------
extern "C" void kernel_launch(void* const* d_in, const int* in_sizes, int n_in,
                              void* d_out, int out_size, void* d_ws, size_t ws_size,
                              hipStream_t stream) {
  const float* x  = (const float*)d_in[0];
  const float* Wq = (const float*)d_in[1];
  const float* Wk = (const float*)d_in[2];
  const float* Wv = (const float*)d_in[3];
  const float* We = (const float*)d_in[4];
  const float* bE = (const float*)d_in[5];
  const float* Wf = (const float*)d_in[6];
  const float* bF = (const float*)d_in[7];
  const float* Wo = (const float*)d_in[8];
  const float* bo = (const float*)d_in[9];
  float* out = (float*)d_out;

  char* ws = (char*)d_ws;
  u16* xb   = (u16*)(ws);                 // 16,777,216 B  [8192][1024] bf16
  u16* Wqkv = (u16*)(ws + 16777216);      //  6,291,456 B  [3072][1024] bf16
  u16* Wob  = (u16*)(ws + 23068672);      //  2,097,152 B  [1024][1024] bf16
  u16* QKV  = (u16*)(ws + 25165824);      // 50,331,648 B  [8192][3072] bf16
  u16* KeT  = (u16*)(ws + 75497472);      //  1,048,576 B  [32][256][64] bf16
  u16* Vf   = (u16*)(ws + 76546048);      //  1,048,576 B  [32][64][256] bf16
  u16* attn = (u16*)(ws + 77594624);      // 16,777,216 B  [8192][1024] bf16

  cast_f32_bf16<<<8192, 256, 0, stream>>>(x, xb, 2097152);
  cast_f32_bf16<<<1024, 256, 0, stream>>>(Wq, Wqkv, 262144);
  cast_f32_bf16<<<1024, 256, 0, stream>>>(Wk, Wqkv + 1048576, 262144);
  cast_f32_bf16<<<1024, 256, 0, stream>>>(Wv, Wqkv + 2097152, 262144);
  cast_f32_bf16<<<1024, 256, 0, stream>>>(Wo, Wob, 262144);

  // QKV projection: [8192,3072] = x[8192,1024] @ Wqkv[3072,1024]^T
  gemm_bt<0><<<dim3(24, 64), 256, 0, stream>>>(xb, Wqkv, QKV, nullptr,
                                               1024, 1024, 1024, 3072);
  // Ke/Vf low-rank projections
  kevf_kernel<<<dim3(4, 32, 2), 256, 0, stream>>>(We, bE, Wf, bF, QKV, KeT, Vf);
  // fused scores/softmax/PV/gelu
  attn_fused<<<dim3(64, 32), 256, 0, stream>>>(QKV, KeT, Vf, attn);
  // output projection + bias
  gemm_bt<1><<<dim3(8, 64), 256, 0, stream>>>(attn, Wob, out, bo,
                                              1024, 1024, 1024, 1024);
}

// Round 5
// 223.715 us; speedup vs baseline: 1.4165x; 1.4108x over previous
//
#include <hip/hip_runtime.h>

// ---------- types & helpers ----------
typedef unsigned short u16;
typedef float f32x4 __attribute__((ext_vector_type(4)));
typedef short s16x8 __attribute__((ext_vector_type(8)));
typedef unsigned short u16x4 __attribute__((ext_vector_type(4)));

__device__ __forceinline__ u16 f2bf(float f) {
  union { float f; unsigned u; } v; v.f = f;
  unsigned r = v.u + 0x7FFFu + ((v.u >> 16) & 1u);   // RNE
  return (u16)(r >> 16);
}

__device__ __forceinline__ void gload_lds16(const void* g, void* l) {
  __builtin_amdgcn_global_load_lds(
      (const __attribute__((address_space(1))) void*)g,
      (__attribute__((address_space(3))) void*)l, 16, 0, 0);
}

// ---------- fp32 -> bf16 cast ----------
__global__ __launch_bounds__(256) void cast_f32_bf16(
    const float* __restrict__ src, u16* __restrict__ dst, int n4) {
  int i = blockIdx.x * 256 + threadIdx.x;
  if (i >= n4) return;
  f32x4 v = ((const f32x4*)src)[i];
  u16x4 o = { f2bf(v[0]), f2bf(v[1]), f2bf(v[2]), f2bf(v[3]) };
  ((u16x4*)dst)[i] = o;
}

// ---------- bt-GEMM: C[M,N] = A[M,K] * B[N,K]^T  (bf16 in, fp32 acc) ----------
// 128x128 tile, BK=32, 256 threads (4 waves in 2x2), m97 structure.
// FINAL=0: bf16 C, no bias.  FINAL=1: fp32 C + bias[col].
template <int FINAL>
__global__ __launch_bounds__(256) void gemm_bt(
    const u16* __restrict__ A, const u16* __restrict__ B,
    void* __restrict__ Cout, const float* __restrict__ bias,
    int K, int lda, int ldb, int ldc) {
  __shared__ u16 As[128 * 32];
  __shared__ u16 Bs[128 * 32];
  const int tid = threadIdx.x;
  const int wid = tid >> 6, lane = tid & 63;
  const int lo = lane & 15, hi = lane >> 4;
  const int wr = wid >> 1, wc = wid & 1;
  const long brow = (long)blockIdx.y * 128;
  const long bcol = (long)blockIdx.x * 128;

  f32x4 acc[4][4] = {};

  const char* Ab = (const char*)(A + (size_t)brow * lda);
  const char* Bb = (const char*)(B + (size_t)bcol * ldb);
  const int ldab = lda * 2, ldbb = ldb * 2;

  for (int k0 = 0; k0 < K; k0 += 32) {
#pragma unroll
    for (int i = 0; i < 2; ++i) {
      int ob = wid * 2048 + i * 1024;    // wave-uniform LDS base
      int o = ob + lane * 16;
      int row = o >> 6, cb = o & 63;
      gload_lds16(Ab + (size_t)row * ldab + k0 * 2 + cb, (char*)As + ob);
      gload_lds16(Bb + (size_t)row * ldbb + k0 * 2 + cb, (char*)Bs + ob);
    }
    __syncthreads();   // drains vmcnt(0) then barrier
    s16x8 af[4], bfr[4];
#pragma unroll
    for (int m = 0; m < 4; ++m)
      af[m] = *(const s16x8*)&As[(wr * 64 + m * 16 + lo) * 32 + hi * 8];
#pragma unroll
    for (int n = 0; n < 4; ++n)
      bfr[n] = *(const s16x8*)&Bs[(wc * 64 + n * 16 + lo) * 32 + hi * 8];
#pragma unroll
    for (int m = 0; m < 4; ++m)
#pragma unroll
      for (int n = 0; n < 4; ++n)
        acc[m][n] = __builtin_amdgcn_mfma_f32_16x16x32_bf16(af[m], bfr[n], acc[m][n], 0, 0, 0);
    __syncthreads();
  }
#pragma unroll
  for (int m = 0; m < 4; ++m) {
#pragma unroll
    for (int n = 0; n < 4; ++n) {
#pragma unroll
      for (int r = 0; r < 4; ++r) {
        size_t row = brow + wr * 64 + m * 16 + hi * 4 + r;
        size_t col = bcol + wc * 64 + n * 16 + lo;
        float v = acc[m][n][r];
        if (FINAL) ((float*)Cout)[row * ldc + col] = v + bias[col];
        else       ((u16*)Cout)[row * ldc + col] = f2bf(v);
      }
    }
  }
}

// ---------- Ke/Vf partial: per (kc, bh, type*4+ns) block: 64k x 64d over 1024 n ----------
// part[tb][ns][kkl*64+dd] fp32, tb = (type*32+bh)*4+kc
__global__ __launch_bounds__(256) void kevf_kernel(
    const float* __restrict__ We, const float* __restrict__ Wf,
    const u16* __restrict__ QKV, float* __restrict__ part) {
  __shared__ u16 Wa[64 * 32];   // [kk][n] bf16, xor-swizzled 16B slots
  __shared__ u16 Vt[64 * 32];   // [dd][n] bf16, n xor-swizzled by dd
  const int type = blockIdx.z >> 2, ns = blockIdx.z & 3;
  const int bh = blockIdx.y, b = bh >> 4, h = bh & 15;
  const int kk0 = blockIdx.x * 64;
  const float* W = (type ? Wf : We) + ((size_t)(h * 256 + kk0)) * 4096;
  const int col0 = (type ? 2048 : 1024) + h * 64;
  const int tid = threadIdx.x, wid = tid >> 6, lane = tid & 63;
  const int lo = lane & 15, hi = lane >> 4;

  f32x4 acc[4] = {};

  const int nbeg = ns << 10, nend = nbeg + 1024;
  for (int n0 = nbeg; n0 < nend; n0 += 32) {
    { // stage W (fp32 -> bf16)
      int r = tid >> 2, c8 = (tid & 3) * 8;
      const f32x4* wp = (const f32x4*)(W + (size_t)r * 4096 + n0 + c8);
      f32x4 v0 = wp[0], v1 = wp[1];
      s16x8 wv;
      wv[0] = (short)f2bf(v0[0]); wv[1] = (short)f2bf(v0[1]);
      wv[2] = (short)f2bf(v0[2]); wv[3] = (short)f2bf(v0[3]);
      wv[4] = (short)f2bf(v1[0]); wv[5] = (short)f2bf(v1[1]);
      wv[6] = (short)f2bf(v1[2]); wv[7] = (short)f2bf(v1[3]);
      *(s16x8*)((char*)Wa + r * 64 + ((c8 * 2) ^ ((r & 3) << 4))) = wv;
    }
    { // stage K/V transposed
      int n = tid >> 3, dd0 = (tid & 7) * 8;
      s16x8 v = *(const s16x8*)(QKV + (size_t)(b * 4096 + n0 + n) * 3072 + col0 + dd0);
#pragma unroll
      for (int q = 0; q < 8; ++q) {
        int dd = dd0 + q;
        Vt[dd * 32 + (n ^ (((dd >> 3) & 3) << 3))] = (u16)v[q];
      }
    }
    __syncthreads();
    int rr = wid * 16 + lo;
    s16x8 a = *(const s16x8*)((const char*)Wa + rr * 64 + ((hi * 16) ^ ((rr & 3) << 4)));
#pragma unroll
    for (int dt = 0; dt < 4; ++dt) {
      int dd = dt * 16 + lo;
      s16x8 bv = *(const s16x8*)&Vt[dd * 32 + ((hi * 8) ^ (((dd >> 3) & 3) << 3))];
      acc[dt] = __builtin_amdgcn_mfma_f32_16x16x32_bf16(a, bv, acc[dt], 0, 0, 0);
    }
    __syncthreads();
  }
  const size_t pbase = ((size_t)((type * 32 + bh) * 4 + blockIdx.x) * 4 + ns) * 4096;
#pragma unroll
  for (int dt = 0; dt < 4; ++dt)
#pragma unroll
    for (int r = 0; r < 4; ++r) {
      int kkl = wid * 16 + hi * 4 + r;
      int dd = dt * 16 + lo;
      part[pbase + kkl * 64 + dd] = acc[dt][r];
    }
}

// ---------- reduce 4 n-splits, add bias, write KeT (type0) / Vf (type1) ----------
__global__ __launch_bounds__(256) void kevf_reduce(
    const float* __restrict__ part, const float* __restrict__ bE,
    const float* __restrict__ bF, u16* __restrict__ KeT, u16* __restrict__ Vf) {
  const int tb = blockIdx.x;
  const int type = tb >> 7, bh = (tb >> 2) & 31, kc = tb & 3;
  const int t = threadIdx.x;
  const int kkl = t >> 2, dd0 = (t & 3) * 16;
  const float* p = part + (size_t)tb * 16384 + kkl * 64 + dd0;
  f32x4 s[4];
#pragma unroll
  for (int j = 0; j < 4; ++j) s[j] = ((const f32x4*)p)[j];
#pragma unroll
  for (int ns = 1; ns < 4; ++ns)
#pragma unroll
    for (int j = 0; j < 4; ++j) {
      f32x4 v = ((const f32x4*)(p + ns * 4096))[j];
      s[j][0] += v[0]; s[j][1] += v[1]; s[j][2] += v[2]; s[j][3] += v[3];
    }
  const int kk = kc * 64 + kkl;
  const float bias = (type ? bF : bE)[(bh & 15) * 256 + kk];
  if (type == 0) {
    u16* o = KeT + ((size_t)bh * 256 + kk) * 64 + dd0;
#pragma unroll
    for (int j = 0; j < 4; ++j) {
      u16x4 w = { f2bf(s[j][0] + bias), f2bf(s[j][1] + bias),
                  f2bf(s[j][2] + bias), f2bf(s[j][3] + bias) };
      *(u16x4*)(o + j * 4) = w;
    }
  } else {
#pragma unroll
    for (int j = 0; j < 4; ++j)
#pragma unroll
      for (int e = 0; e < 4; ++e) {
        int dd = dd0 + j * 4 + e;
        Vf[((size_t)bh * 64 + dd) * 256 + kk] = f2bf(s[j][e] + bias);
      }
  }
}

// ---------- fused attention: scores -> softmax -> PV -> gelu ----------
// grid (64 ntiles, 32 bh); 256 threads = 4 waves x 16 q-rows each.
__global__ __launch_bounds__(256) void attn_fused(
    const u16* __restrict__ QKV, const u16* __restrict__ KeT,
    const u16* __restrict__ Vf, u16* __restrict__ attn) {
  __shared__ char smem[65536];
  char* sKe = smem;           // [256][128B] swizzled (aliased by P later)
  char* sVf = smem + 32768;   // [64][512B] swizzled
  const int tid = threadIdx.x, wid = tid >> 6, lane = tid & 63;
  const int lo = lane & 15, hi = lane >> 4;
  const int bh = blockIdx.y, b = bh >> 4, h = bh & 15;
  const int n0 = blockIdx.x * 64;

  const char* keg = (const char*)(KeT + (size_t)bh * 256 * 64);
  const char* vfg = (const char*)(Vf + (size_t)bh * 64 * 256);
#pragma unroll
  for (int i = 0; i < 8; ++i) {
    int ob = wid * 8192 + i * 1024;
    int o = ob + lane * 16;
    int kr = o >> 7, kc = o & 127;
    gload_lds16(keg + kr * 128 + (kc ^ ((kr & 7) << 4)), sKe + ob);
    int vr = o >> 9, vc = o & 511;
    gload_lds16(vfg + vr * 512 + (vc ^ ((vr & 7) << 4)), sVf + ob);
  }
  const u16* qp = QKV + (size_t)(b * 4096 + n0 + wid * 16 + lo) * 3072 + h * 64;
  s16x8 qf0 = *(const s16x8*)(qp + hi * 8);
  s16x8 qf1 = *(const s16x8*)(qp + 32 + hi * 8);
  __syncthreads();

  f32x4 sc[16];
#pragma unroll
  for (int nt = 0; nt < 16; ++nt) {
    int kk = nt * 16 + lo;
    int sw = (kk & 7) << 4;
    s16x8 b0 = *(const s16x8*)(sKe + kk * 128 + ((hi * 16) ^ sw));
    s16x8 b1 = *(const s16x8*)(sKe + kk * 128 + ((64 + hi * 16) ^ sw));
    f32x4 c = {0.f, 0.f, 0.f, 0.f};
    c = __builtin_amdgcn_mfma_f32_16x16x32_bf16(qf0, b0, c, 0, 0, 0);
    c = __builtin_amdgcn_mfma_f32_16x16x32_bf16(qf1, b1, c, 0, 0, 0);
    sc[nt] = c;
  }
  // softmax over 256 (rows live on 16-lane groups: row = hi*4+r, col = nt*16+lo)
  float mx[4], inv[4];
#pragma unroll
  for (int r = 0; r < 4; ++r) {
    float m = sc[0][r];
#pragma unroll
    for (int nt = 1; nt < 16; ++nt) m = fmaxf(m, sc[nt][r]);
    m = fmaxf(m, __shfl_xor(m, 1));
    m = fmaxf(m, __shfl_xor(m, 2));
    m = fmaxf(m, __shfl_xor(m, 4));
    m = fmaxf(m, __shfl_xor(m, 8));
    mx[r] = m;
  }
  const float SCL = 0.125f * 1.4426950408889634f;   // (1/sqrt(64)) * log2(e)
  float sm[4] = {0.f, 0.f, 0.f, 0.f};
#pragma unroll
  for (int nt = 0; nt < 16; ++nt)
#pragma unroll
    for (int r = 0; r < 4; ++r) {
      float p = exp2f((sc[nt][r] - mx[r]) * SCL);
      sc[nt][r] = p;
      sm[r] += p;
    }
#pragma unroll
  for (int r = 0; r < 4; ++r) {
    float s = sm[r];
    s += __shfl_xor(s, 1);
    s += __shfl_xor(s, 2);
    s += __shfl_xor(s, 4);
    s += __shfl_xor(s, 8);
    inv[r] = 1.0f / s;
  }
  __syncthreads();            // all waves done reading sKe
  char* pb = smem + wid * 8192;  // P aliases sKe region: [16 rows][512B] per wave
#pragma unroll
  for (int nt = 0; nt < 16; ++nt)
#pragma unroll
    for (int r = 0; r < 4; ++r) {
      int row = hi * 4 + r;
      int kk = nt * 16 + lo;
      *(u16*)(pb + row * 512 + ((kk * 2) ^ ((row & 7) << 4))) = f2bf(sc[nt][r] * inv[r]);
    }
  __syncthreads();
  s16x8 pa[8];
#pragma unroll
  for (int ks = 0; ks < 8; ++ks)
    pa[ks] = *(const s16x8*)(pb + lo * 512 + ((ks * 64 + hi * 16) ^ ((lo & 7) << 4)));
#pragma unroll
  for (int dt = 0; dt < 4; ++dt) {
    int dd = dt * 16 + lo;
    int sw = (dd & 7) << 4;
    f32x4 o = {0.f, 0.f, 0.f, 0.f};
#pragma unroll
    for (int ks = 0; ks < 8; ++ks) {
      s16x8 vb = *(const s16x8*)(sVf + dd * 512 + ((ks * 64 + hi * 16) ^ sw));
      o = __builtin_amdgcn_mfma_f32_16x16x32_bf16(pa[ks], vb, o, 0, 0, 0);
    }
#pragma unroll
    for (int r = 0; r < 4; ++r) {
      int row = n0 + wid * 16 + hi * 4 + r;
      float x = o[r];
      float g = 0.5f * x * (1.0f + erff(x * 0.7071067811865476f));
      attn[(size_t)(b * 4096 + row) * 1024 + h * 64 + dd] = f2bf(g);
    }
  }
}

// ---------- launcher ----------
extern "C" void kernel_launch(void* const* d_in, const int* in_sizes, int n_in,
                              void* d_out, int out_size, void* d_ws, size_t ws_size,
                              hipStream_t stream) {
  const float* x  = (const float*)d_in[0];
  const float* Wq = (const float*)d_in[1];
  const float* Wk = (const float*)d_in[2];
  const float* Wv = (const float*)d_in[3];
  const float* We = (const float*)d_in[4];
  const float* bE = (const float*)d_in[5];
  const float* Wf = (const float*)d_in[6];
  const float* bF = (const float*)d_in[7];
  const float* Wo = (const float*)d_in[8];
  const float* bo = (const float*)d_in[9];
  float* out = (float*)d_out;

  char* ws = (char*)d_ws;
  u16* xb   = (u16*)(ws);                 // 16,777,216 B  [8192][1024] bf16
  u16* Wqkv = (u16*)(ws + 16777216);      //  6,291,456 B  [3072][1024] bf16
  u16* Wob  = (u16*)(ws + 23068672);      //  2,097,152 B  [1024][1024] bf16
  u16* QKV  = (u16*)(ws + 25165824);      // 50,331,648 B  [8192][3072] bf16
  u16* KeT  = (u16*)(ws + 75497472);      //  1,048,576 B  [32][256][64] bf16
  u16* Vf   = (u16*)(ws + 76546048);      //  1,048,576 B  [32][64][256] bf16
  u16* attn = (u16*)(ws + 77594624);      // 16,777,216 B  [8192][1024] bf16
  float* part = (float*)(ws);             // 16,777,216 B  aliases xb (dead after QKV GEMM)

  cast_f32_bf16<<<8192, 256, 0, stream>>>(x, xb, 2097152);
  cast_f32_bf16<<<1024, 256, 0, stream>>>(Wq, Wqkv, 262144);
  cast_f32_bf16<<<1024, 256, 0, stream>>>(Wk, Wqkv + 1048576, 262144);
  cast_f32_bf16<<<1024, 256, 0, stream>>>(Wv, Wqkv + 2097152, 262144);
  cast_f32_bf16<<<1024, 256, 0, stream>>>(Wo, Wob, 262144);

  // QKV projection: [8192,3072] = x[8192,1024] @ Wqkv[3072,1024]^T
  gemm_bt<0><<<dim3(24, 64), 256, 0, stream>>>(xb, Wqkv, QKV, nullptr,
                                               1024, 1024, 1024, 3072);
  // Ke/Vf low-rank projections: 4-way n-split partials + reduce
  kevf_kernel<<<dim3(4, 32, 8), 256, 0, stream>>>(We, Wf, QKV, part);
  kevf_reduce<<<256, 256, 0, stream>>>(part, bE, bF, KeT, Vf);
  // fused scores/softmax/PV/gelu
  attn_fused<<<dim3(64, 32), 256, 0, stream>>>(QKV, KeT, Vf, attn);
  // output projection + bias
  gemm_bt<1><<<dim3(8, 64), 256, 0, stream>>>(attn, Wob, out, bo,
                                              1024, 1024, 1024, 1024);
}

// Round 6
// 220.897 us; speedup vs baseline: 1.4345x; 1.0128x over previous
//
#include <hip/hip_runtime.h>

// ---------- types & helpers ----------
typedef unsigned short u16;
typedef float f32x4 __attribute__((ext_vector_type(4)));
typedef short s16x8 __attribute__((ext_vector_type(8)));
typedef unsigned short u16x4 __attribute__((ext_vector_type(4)));

__device__ __forceinline__ u16 f2bf(float f) {
  union { float f; unsigned u; } v; v.f = f;
  unsigned r = v.u + 0x7FFFu + ((v.u >> 16) & 1u);   // RNE
  return (u16)(r >> 16);
}

__device__ __forceinline__ void gload_lds16(const void* g, void* l) {
  __builtin_amdgcn_global_load_lds(
      (const __attribute__((address_space(1))) void*)g,
      (__attribute__((address_space(3))) void*)l, 16, 0, 0);
}

// ---------- fp32 -> bf16 cast ----------
__global__ __launch_bounds__(256) void cast_f32_bf16(
    const float* __restrict__ src, u16* __restrict__ dst, int n4) {
  int i = blockIdx.x * 256 + threadIdx.x;
  if (i >= n4) return;
  f32x4 v = ((const f32x4*)src)[i];
  u16x4 o = { f2bf(v[0]), f2bf(v[1]), f2bf(v[2]), f2bf(v[3]) };
  ((u16x4*)dst)[i] = o;
}

// ---------- pipelined bt-GEMM: C[M,N] = A[M,K] * B[N,K]^T ----------
// BM=128, BN=256, BK=32, 512 threads = 8 waves (2 wm x 4 wn), per-wave 64x64.
// 4-deep LDS pipeline, counted vmcnt (never 0 in steady state), raw barriers.
// FINAL=0: bf16 C, no bias.  FINAL=1: fp32 C + bias[col].
template <int FINAL>
__global__ __launch_bounds__(512) void gemm_pipe(
    const u16* __restrict__ A, const u16* __restrict__ B,
    void* __restrict__ Cout, const float* __restrict__ bias,
    int K, int lda, int ldb, int ldc) {
  __shared__ char smem[4 * 8192 + 4 * 16384];   // 96 KiB: 4x A(8K), 4x B(16K)
  char* sA = smem;            // buf s: [128 rows][64 B] (XOR-swizzled content)
  char* sB = smem + 32768;    // buf s: [256 rows][64 B]
  const int tid = threadIdx.x;
  const int wid = tid >> 6, lane = tid & 63;
  const int lo = lane & 15, hi = lane >> 4;
  const int wm = wid >> 2, wn = wid & 3;
  const long brow = (long)blockIdx.y * 128;
  const long bcol = (long)blockIdx.x * 256;
  const int T = K >> 5;

  f32x4 acc[4][4] = {};

  const char* Ab = (const char*)(A + (size_t)brow * lda);
  const char* Bb = (const char*)(B + (size_t)bcol * ldb);
  const size_t ldab = (size_t)lda * 2, ldbb = (size_t)ldb * 2;

  // staging geometry: per wave per tile = 1 A-chunk + 2 B-chunks (1 KiB each).
  // LDS is written linearly (wave base + lane*16); the XOR swizzle is applied
  // to the GLOBAL source column, so LDS[row][c] = G[row][c ^ ((row&3)<<4)].
  const int aoff = wid * 1024 + lane * 16;
  const int arow = aoff >> 6, acb = aoff & 63;
  const char* asrc = Ab + (size_t)arow * ldab + (acb ^ ((arow & 3) << 4));
  const int boff0 = (wid * 2) * 1024 + lane * 16;
  const int brw0 = boff0 >> 6, bcb0 = boff0 & 63;
  const char* bsrc0 = Bb + (size_t)brw0 * ldbb + (bcb0 ^ ((brw0 & 3) << 4));
  const int boff1 = (wid * 2 + 1) * 1024 + lane * 16;
  const int brw1 = boff1 >> 6, bcb1 = boff1 & 63;
  const char* bsrc1 = Bb + (size_t)brw1 * ldbb + (bcb1 ^ ((brw1 & 3) << 4));

  // frag read byte-offsets (row&3 == lo&3 since row bases are 16-aligned)
  int ra[4], rb[4];
#pragma unroll
  for (int m = 0; m < 4; ++m)
    ra[m] = (wm * 64 + m * 16 + lo) * 64 + ((hi * 16) ^ ((lo & 3) << 4));
#pragma unroll
  for (int n = 0; n < 4; ++n)
    rb[n] = (wn * 64 + n * 16 + lo) * 64 + ((hi * 16) ^ ((lo & 3) << 4));

#define STAGE(t)                                                         \
  {                                                                      \
    int s_ = (t) & 3;                                                    \
    size_t kb_ = (size_t)(t) << 6;                                       \
    gload_lds16(asrc + kb_, sA + s_ * 8192 + wid * 1024);                \
    gload_lds16(bsrc0 + kb_, sB + s_ * 16384 + wid * 2048);              \
    gload_lds16(bsrc1 + kb_, sB + s_ * 16384 + wid * 2048 + 1024);       \
  }

  // prologue: 3 tiles in flight, wait for tile 0 (3 oldest of 9 loads)
  STAGE(0); STAGE(1); STAGE(2);
  asm volatile("s_waitcnt vmcnt(6)" ::: "memory");
  __builtin_amdgcn_s_barrier();
  __builtin_amdgcn_sched_barrier(0);

  for (int t = 0; t < T; ++t) {
    const char* bufA = sA + (t & 3) * 8192;
    const char* bufB = sB + (t & 3) * 16384;
    s16x8 af[4], bf[4];
#pragma unroll
    for (int m = 0; m < 4; ++m) af[m] = *(const s16x8*)(bufA + ra[m]);
#pragma unroll
    for (int n = 0; n < 4; ++n) bf[n] = *(const s16x8*)(bufB + rb[n]);
    if (t + 3 < T) STAGE(t + 3);     // slot (t+3)&3 != t&3: no WAR
    __builtin_amdgcn_s_setprio(1);
#pragma unroll
    for (int m = 0; m < 4; ++m)
#pragma unroll
      for (int n = 0; n < 4; ++n)
        acc[m][n] = __builtin_amdgcn_mfma_f32_16x16x32_bf16(af[m], bf[n], acc[m][n], 0, 0, 0);
    __builtin_amdgcn_s_setprio(0);
    // keep tiles t+2, t+3 (6 loads) in flight; tile t+1 must have landed
    int rem = T - 2 - t;
    if (rem >= 2)      asm volatile("s_waitcnt vmcnt(6)" ::: "memory");
    else if (rem == 1) asm volatile("s_waitcnt vmcnt(3)" ::: "memory");
    else               asm volatile("s_waitcnt vmcnt(0)" ::: "memory");
    __builtin_amdgcn_s_barrier();
    __builtin_amdgcn_sched_barrier(0);
  }
#undef STAGE

#pragma unroll
  for (int m = 0; m < 4; ++m) {
#pragma unroll
    for (int n = 0; n < 4; ++n) {
#pragma unroll
      for (int r = 0; r < 4; ++r) {
        size_t row = brow + wm * 64 + m * 16 + hi * 4 + r;
        size_t col = bcol + wn * 64 + n * 16 + lo;
        float v = acc[m][n][r];
        if (FINAL) ((float*)Cout)[row * ldc + col] = v + bias[col];
        else       ((u16*)Cout)[row * ldc + col] = f2bf(v);
      }
    }
  }
}

// ---------- Ke/Vf partial: per (kc, bh, type*4+ns) block: 64k x 64d over 1024 n ----------
__global__ __launch_bounds__(256) void kevf_kernel(
    const float* __restrict__ We, const float* __restrict__ Wf,
    const u16* __restrict__ QKV, float* __restrict__ part) {
  __shared__ u16 Wa[64 * 32];   // [kk][n] bf16, xor-swizzled 16B slots
  __shared__ u16 Vt[64 * 32];   // [dd][n] bf16, n xor-swizzled by dd
  const int type = blockIdx.z >> 2, ns = blockIdx.z & 3;
  const int bh = blockIdx.y, b = bh >> 4, h = bh & 15;
  const int kk0 = blockIdx.x * 64;
  const float* W = (type ? Wf : We) + ((size_t)(h * 256 + kk0)) * 4096;
  const int col0 = (type ? 2048 : 1024) + h * 64;
  const int tid = threadIdx.x, wid = tid >> 6, lane = tid & 63;
  const int lo = lane & 15, hi = lane >> 4;

  f32x4 acc[4] = {};

  const int nbeg = ns << 10, nend = nbeg + 1024;
  for (int n0 = nbeg; n0 < nend; n0 += 32) {
    { // stage W (fp32 -> bf16)
      int r = tid >> 2, c8 = (tid & 3) * 8;
      const f32x4* wp = (const f32x4*)(W + (size_t)r * 4096 + n0 + c8);
      f32x4 v0 = wp[0], v1 = wp[1];
      s16x8 wv;
      wv[0] = (short)f2bf(v0[0]); wv[1] = (short)f2bf(v0[1]);
      wv[2] = (short)f2bf(v0[2]); wv[3] = (short)f2bf(v0[3]);
      wv[4] = (short)f2bf(v1[0]); wv[5] = (short)f2bf(v1[1]);
      wv[6] = (short)f2bf(v1[2]); wv[7] = (short)f2bf(v1[3]);
      *(s16x8*)((char*)Wa + r * 64 + ((c8 * 2) ^ ((r & 3) << 4))) = wv;
    }
    { // stage K/V transposed
      int n = tid >> 3, dd0 = (tid & 7) * 8;
      s16x8 v = *(const s16x8*)(QKV + (size_t)(b * 4096 + n0 + n) * 3072 + col0 + dd0);
#pragma unroll
      for (int q = 0; q < 8; ++q) {
        int dd = dd0 + q;
        Vt[dd * 32 + (n ^ (((dd >> 3) & 3) << 3))] = (u16)v[q];
      }
    }
    __syncthreads();
    int rr = wid * 16 + lo;
    s16x8 a = *(const s16x8*)((const char*)Wa + rr * 64 + ((hi * 16) ^ ((rr & 3) << 4)));
#pragma unroll
    for (int dt = 0; dt < 4; ++dt) {
      int dd = dt * 16 + lo;
      s16x8 bv = *(const s16x8*)&Vt[dd * 32 + ((hi * 8) ^ (((dd >> 3) & 3) << 3))];
      acc[dt] = __builtin_amdgcn_mfma_f32_16x16x32_bf16(a, bv, acc[dt], 0, 0, 0);
    }
    __syncthreads();
  }
  const size_t pbase = ((size_t)((type * 32 + bh) * 4 + blockIdx.x) * 4 + ns) * 4096;
#pragma unroll
  for (int dt = 0; dt < 4; ++dt)
#pragma unroll
    for (int r = 0; r < 4; ++r) {
      int kkl = wid * 16 + hi * 4 + r;
      int dd = dt * 16 + lo;
      part[pbase + kkl * 64 + dd] = acc[dt][r];
    }
}

// ---------- reduce 4 n-splits, add bias, write KeT (type0) / Vf (type1) ----------
__global__ __launch_bounds__(256) void kevf_reduce(
    const float* __restrict__ part, const float* __restrict__ bE,
    const float* __restrict__ bF, u16* __restrict__ KeT, u16* __restrict__ Vf) {
  const int tb = blockIdx.x;
  const int type = tb >> 7, bh = (tb >> 2) & 31, kc = tb & 3;
  const int t = threadIdx.x;
  const int kkl = t >> 2, dd0 = (t & 3) * 16;
  const float* p = part + (size_t)tb * 16384 + kkl * 64 + dd0;
  f32x4 s[4];
#pragma unroll
  for (int j = 0; j < 4; ++j) s[j] = ((const f32x4*)p)[j];
#pragma unroll
  for (int ns = 1; ns < 4; ++ns)
#pragma unroll
    for (int j = 0; j < 4; ++j) {
      f32x4 v = ((const f32x4*)(p + ns * 4096))[j];
      s[j][0] += v[0]; s[j][1] += v[1]; s[j][2] += v[2]; s[j][3] += v[3];
    }
  const int kk = kc * 64 + kkl;
  const float bias = (type ? bF : bE)[(bh & 15) * 256 + kk];
  if (type == 0) {
    u16* o = KeT + ((size_t)bh * 256 + kk) * 64 + dd0;
#pragma unroll
    for (int j = 0; j < 4; ++j) {
      u16x4 w = { f2bf(s[j][0] + bias), f2bf(s[j][1] + bias),
                  f2bf(s[j][2] + bias), f2bf(s[j][3] + bias) };
      *(u16x4*)(o + j * 4) = w;
    }
  } else {
#pragma unroll
    for (int j = 0; j < 4; ++j)
#pragma unroll
      for (int e = 0; e < 4; ++e) {
        int dd = dd0 + j * 4 + e;
        Vf[((size_t)bh * 64 + dd) * 256 + kk] = f2bf(s[j][e] + bias);
      }
  }
}

// ---------- fused attention: scores -> softmax -> PV -> gelu ----------
__global__ __launch_bounds__(256) void attn_fused(
    const u16* __restrict__ QKV, const u16* __restrict__ KeT,
    const u16* __restrict__ Vf, u16* __restrict__ attn) {
  __shared__ char smem[65536];
  char* sKe = smem;           // [256][128B] swizzled (aliased by P later)
  char* sVf = smem + 32768;   // [64][512B] swizzled
  const int tid = threadIdx.x, wid = tid >> 6, lane = tid & 63;
  const int lo = lane & 15, hi = lane >> 4;
  const int bh = blockIdx.y, b = bh >> 4, h = bh & 15;
  const int n0 = blockIdx.x * 64;

  const char* keg = (const char*)(KeT + (size_t)bh * 256 * 64);
  const char* vfg = (const char*)(Vf + (size_t)bh * 64 * 256);
#pragma unroll
  for (int i = 0; i < 8; ++i) {
    int ob = wid * 8192 + i * 1024;
    int o = ob + lane * 16;
    int kr = o >> 7, kc = o & 127;
    gload_lds16(keg + kr * 128 + (kc ^ ((kr & 7) << 4)), sKe + ob);
    int vr = o >> 9, vc = o & 511;
    gload_lds16(vfg + vr * 512 + (vc ^ ((vr & 7) << 4)), sVf + ob);
  }
  const u16* qp = QKV + (size_t)(b * 4096 + n0 + wid * 16 + lo) * 3072 + h * 64;
  s16x8 qf0 = *(const s16x8*)(qp + hi * 8);
  s16x8 qf1 = *(const s16x8*)(qp + 32 + hi * 8);
  __syncthreads();

  f32x4 sc[16];
#pragma unroll
  for (int nt = 0; nt < 16; ++nt) {
    int kk = nt * 16 + lo;
    int sw = (kk & 7) << 4;
    s16x8 b0 = *(const s16x8*)(sKe + kk * 128 + ((hi * 16) ^ sw));
    s16x8 b1 = *(const s16x8*)(sKe + kk * 128 + ((64 + hi * 16) ^ sw));
    f32x4 c = {0.f, 0.f, 0.f, 0.f};
    c = __builtin_amdgcn_mfma_f32_16x16x32_bf16(qf0, b0, c, 0, 0, 0);
    c = __builtin_amdgcn_mfma_f32_16x16x32_bf16(qf1, b1, c, 0, 0, 0);
    sc[nt] = c;
  }
  float mx[4], inv[4];
#pragma unroll
  for (int r = 0; r < 4; ++r) {
    float m = sc[0][r];
#pragma unroll
    for (int nt = 1; nt < 16; ++nt) m = fmaxf(m, sc[nt][r]);
    m = fmaxf(m, __shfl_xor(m, 1));
    m = fmaxf(m, __shfl_xor(m, 2));
    m = fmaxf(m, __shfl_xor(m, 4));
    m = fmaxf(m, __shfl_xor(m, 8));
    mx[r] = m;
  }
  const float SCL = 0.125f * 1.4426950408889634f;   // (1/sqrt(64)) * log2(e)
  float sm[4] = {0.f, 0.f, 0.f, 0.f};
#pragma unroll
  for (int nt = 0; nt < 16; ++nt)
#pragma unroll
    for (int r = 0; r < 4; ++r) {
      float p = exp2f((sc[nt][r] - mx[r]) * SCL);
      sc[nt][r] = p;
      sm[r] += p;
    }
#pragma unroll
  for (int r = 0; r < 4; ++r) {
    float s = sm[r];
    s += __shfl_xor(s, 1);
    s += __shfl_xor(s, 2);
    s += __shfl_xor(s, 4);
    s += __shfl_xor(s, 8);
    inv[r] = 1.0f / s;
  }
  __syncthreads();            // all waves done reading sKe
  char* pb = smem + wid * 8192;  // P aliases sKe region: [16 rows][512B] per wave
#pragma unroll
  for (int nt = 0; nt < 16; ++nt)
#pragma unroll
    for (int r = 0; r < 4; ++r) {
      int row = hi * 4 + r;
      int kk = nt * 16 + lo;
      *(u16*)(pb + row * 512 + ((kk * 2) ^ ((row & 7) << 4))) = f2bf(sc[nt][r] * inv[r]);
    }
  __syncthreads();
  s16x8 pa[8];
#pragma unroll
  for (int ks = 0; ks < 8; ++ks)
    pa[ks] = *(const s16x8*)(pb + lo * 512 + ((ks * 64 + hi * 16) ^ ((lo & 7) << 4)));
#pragma unroll
  for (int dt = 0; dt < 4; ++dt) {
    int dd = dt * 16 + lo;
    int sw = (dd & 7) << 4;
    f32x4 o = {0.f, 0.f, 0.f, 0.f};
#pragma unroll
    for (int ks = 0; ks < 8; ++ks) {
      s16x8 vb = *(const s16x8*)(sVf + dd * 512 + ((ks * 64 + hi * 16) ^ sw));
      o = __builtin_amdgcn_mfma_f32_16x16x32_bf16(pa[ks], vb, o, 0, 0, 0);
    }
#pragma unroll
    for (int r = 0; r < 4; ++r) {
      int row = n0 + wid * 16 + hi * 4 + r;
      float x = o[r];
      float g = 0.5f * x * (1.0f + erff(x * 0.7071067811865476f));
      attn[(size_t)(b * 4096 + row) * 1024 + h * 64 + dd] = f2bf(g);
    }
  }
}

// ---------- launcher ----------
extern "C" void kernel_launch(void* const* d_in, const int* in_sizes, int n_in,
                              void* d_out, int out_size, void* d_ws, size_t ws_size,
                              hipStream_t stream) {
  const float* x  = (const float*)d_in[0];
  const float* Wq = (const float*)d_in[1];
  const float* Wk = (const float*)d_in[2];
  const float* Wv = (const float*)d_in[3];
  const float* We = (const float*)d_in[4];
  const float* bE = (const float*)d_in[5];
  const float* Wf = (const float*)d_in[6];
  const float* bF = (const float*)d_in[7];
  const float* Wo = (const float*)d_in[8];
  const float* bo = (const float*)d_in[9];
  float* out = (float*)d_out;

  char* ws = (char*)d_ws;
  u16* xb   = (u16*)(ws);                 // 16,777,216 B  [8192][1024] bf16
  u16* Wqkv = (u16*)(ws + 16777216);      //  6,291,456 B  [3072][1024] bf16
  u16* Wob  = (u16*)(ws + 23068672);      //  2,097,152 B  [1024][1024] bf16
  u16* QKV  = (u16*)(ws + 25165824);      // 50,331,648 B  [8192][3072] bf16
  u16* KeT  = (u16*)(ws + 75497472);      //  1,048,576 B  [32][256][64] bf16
  u16* Vf   = (u16*)(ws + 76546048);      //  1,048,576 B  [32][64][256] bf16
  u16* attn = (u16*)(ws + 77594624);      // 16,777,216 B  [8192][1024] bf16
  float* part = (float*)(ws);             // 16,777,216 B  aliases xb (dead after QKV GEMM)

  cast_f32_bf16<<<8192, 256, 0, stream>>>(x, xb, 2097152);
  cast_f32_bf16<<<1024, 256, 0, stream>>>(Wq, Wqkv, 262144);
  cast_f32_bf16<<<1024, 256, 0, stream>>>(Wk, Wqkv + 1048576, 262144);
  cast_f32_bf16<<<1024, 256, 0, stream>>>(Wv, Wqkv + 2097152, 262144);
  cast_f32_bf16<<<1024, 256, 0, stream>>>(Wo, Wob, 262144);

  // QKV projection: [8192,3072] = x[8192,1024] @ Wqkv[3072,1024]^T
  gemm_pipe<0><<<dim3(12, 64), 512, 0, stream>>>(xb, Wqkv, QKV, nullptr,
                                                 1024, 1024, 1024, 3072);
  // Ke/Vf low-rank projections: 4-way n-split partials + reduce
  kevf_kernel<<<dim3(4, 32, 8), 256, 0, stream>>>(We, Wf, QKV, part);
  kevf_reduce<<<256, 256, 0, stream>>>(part, bE, bF, KeT, Vf);
  // fused scores/softmax/PV/gelu
  attn_fused<<<dim3(64, 32), 256, 0, stream>>>(QKV, KeT, Vf, attn);
  // output projection + bias
  gemm_pipe<1><<<dim3(4, 64), 512, 0, stream>>>(attn, Wob, out, bo,
                                                1024, 1024, 1024, 1024);
}

// Round 7
// 216.386 us; speedup vs baseline: 1.4644x; 1.0208x over previous
//
#include <hip/hip_runtime.h>

// ---------- types & helpers ----------
typedef unsigned short u16;
typedef float f32x4 __attribute__((ext_vector_type(4)));
typedef short s16x8 __attribute__((ext_vector_type(8)));
typedef unsigned short u16x4 __attribute__((ext_vector_type(4)));

__device__ __forceinline__ u16 f2bf(float f) {
  union { float f; unsigned u; } v; v.f = f;
  unsigned r = v.u + 0x7FFFu + ((v.u >> 16) & 1u);   // RNE
  return (u16)(r >> 16);
}

__device__ __forceinline__ void gload_lds16(const void* g, void* l) {
  __builtin_amdgcn_global_load_lds(
      (const __attribute__((address_space(1))) void*)g,
      (__attribute__((address_space(3))) void*)l, 16, 0, 0);
}

// ---------- fp32 -> bf16 cast ----------
__global__ __launch_bounds__(256) void cast_f32_bf16(
    const float* __restrict__ src, u16* __restrict__ dst, int n4) {
  int i = blockIdx.x * 256 + threadIdx.x;
  if (i >= n4) return;
  f32x4 v = ((const f32x4*)src)[i];
  u16x4 o = { f2bf(v[0]), f2bf(v[1]), f2bf(v[2]), f2bf(v[3]) };
  ((u16x4*)dst)[i] = o;
}

// ---------- pipelined bt-GEMM: C[M,N] = A[M,K] * B[N,K]^T ----------
// BM=128, BN=256, BK=32, 512 threads = 8 waves (2 wm x 4 wn), per-wave 64x64.
// 4-deep LDS pipeline, counted vmcnt (never 0 in steady state), raw barriers.
// FINAL=0: bf16 C, no bias.  FINAL=1: fp32 C + bias[col].
template <int FINAL>
__global__ __launch_bounds__(512) void gemm_pipe(
    const u16* __restrict__ A, const u16* __restrict__ B,
    void* __restrict__ Cout, const float* __restrict__ bias,
    int K, int lda, int ldb, int ldc) {
  __shared__ char smem[4 * 8192 + 4 * 16384];   // 96 KiB: 4x A(8K), 4x B(16K)
  char* sA = smem;            // buf s: [128 rows][64 B] (XOR-swizzled content)
  char* sB = smem + 32768;    // buf s: [256 rows][64 B]
  const int tid = threadIdx.x;
  const int wid = tid >> 6, lane = tid & 63;
  const int lo = lane & 15, hi = lane >> 4;
  const int wm = wid >> 2, wn = wid & 3;
  const long brow = (long)blockIdx.y * 128;
  const long bcol = (long)blockIdx.x * 256;
  const int T = K >> 5;

  f32x4 acc[4][4] = {};

  const char* Ab = (const char*)(A + (size_t)brow * lda);
  const char* Bb = (const char*)(B + (size_t)bcol * ldb);
  const size_t ldab = (size_t)lda * 2, ldbb = (size_t)ldb * 2;

  const int aoff = wid * 1024 + lane * 16;
  const int arow = aoff >> 6, acb = aoff & 63;
  const char* asrc = Ab + (size_t)arow * ldab + (acb ^ ((arow & 3) << 4));
  const int boff0 = (wid * 2) * 1024 + lane * 16;
  const int brw0 = boff0 >> 6, bcb0 = boff0 & 63;
  const char* bsrc0 = Bb + (size_t)brw0 * ldbb + (bcb0 ^ ((brw0 & 3) << 4));
  const int boff1 = (wid * 2 + 1) * 1024 + lane * 16;
  const int brw1 = boff1 >> 6, bcb1 = boff1 & 63;
  const char* bsrc1 = Bb + (size_t)brw1 * ldbb + (bcb1 ^ ((brw1 & 3) << 4));

  int ra[4], rb[4];
#pragma unroll
  for (int m = 0; m < 4; ++m)
    ra[m] = (wm * 64 + m * 16 + lo) * 64 + ((hi * 16) ^ ((lo & 3) << 4));
#pragma unroll
  for (int n = 0; n < 4; ++n)
    rb[n] = (wn * 64 + n * 16 + lo) * 64 + ((hi * 16) ^ ((lo & 3) << 4));

#define STAGE(t)                                                         \
  {                                                                      \
    int s_ = (t) & 3;                                                    \
    size_t kb_ = (size_t)(t) << 6;                                       \
    gload_lds16(asrc + kb_, sA + s_ * 8192 + wid * 1024);                \
    gload_lds16(bsrc0 + kb_, sB + s_ * 16384 + wid * 2048);              \
    gload_lds16(bsrc1 + kb_, sB + s_ * 16384 + wid * 2048 + 1024);       \
  }

  STAGE(0); STAGE(1); STAGE(2);
  asm volatile("s_waitcnt vmcnt(6)" ::: "memory");
  __builtin_amdgcn_s_barrier();
  __builtin_amdgcn_sched_barrier(0);

  for (int t = 0; t < T; ++t) {
    const char* bufA = sA + (t & 3) * 8192;
    const char* bufB = sB + (t & 3) * 16384;
    s16x8 af[4], bf[4];
#pragma unroll
    for (int m = 0; m < 4; ++m) af[m] = *(const s16x8*)(bufA + ra[m]);
#pragma unroll
    for (int n = 0; n < 4; ++n) bf[n] = *(const s16x8*)(bufB + rb[n]);
    if (t + 3 < T) STAGE(t + 3);     // slot (t+3)&3 != t&3: no WAR
    __builtin_amdgcn_s_setprio(1);
#pragma unroll
    for (int m = 0; m < 4; ++m)
#pragma unroll
      for (int n = 0; n < 4; ++n)
        acc[m][n] = __builtin_amdgcn_mfma_f32_16x16x32_bf16(af[m], bf[n], acc[m][n], 0, 0, 0);
    __builtin_amdgcn_s_setprio(0);
    int rem = T - 2 - t;
    if (rem >= 2)      asm volatile("s_waitcnt vmcnt(6)" ::: "memory");
    else if (rem == 1) asm volatile("s_waitcnt vmcnt(3)" ::: "memory");
    else               asm volatile("s_waitcnt vmcnt(0)" ::: "memory");
    __builtin_amdgcn_s_barrier();
    __builtin_amdgcn_sched_barrier(0);
  }
#undef STAGE

#pragma unroll
  for (int m = 0; m < 4; ++m) {
#pragma unroll
    for (int n = 0; n < 4; ++n) {
#pragma unroll
      for (int r = 0; r < 4; ++r) {
        size_t row = brow + wm * 64 + m * 16 + hi * 4 + r;
        size_t col = bcol + wn * 64 + n * 16 + lo;
        float v = acc[m][n][r];
        if (FINAL) ((float*)Cout)[row * ldc + col] = v + bias[col];
        else       ((u16*)Cout)[row * ldc + col] = f2bf(v);
      }
    }
  }
}

// ---------- Ke/Vf partial: per (kc, bh, type*4+ns) block: 64k x 64d over 1024 n ----
// Reg-staged 2-deep pipeline, counted vmcnt, 1 barrier per 32-n step.
__global__ __launch_bounds__(256) void kevf_kernel(
    const float* __restrict__ We, const float* __restrict__ Wf,
    const u16* __restrict__ QKV, float* __restrict__ part) {
  __shared__ u16 Wa[2][64 * 32];   // [kk][n] bf16, xor-swizzled 16B slots
  __shared__ u16 Vt[2][64 * 32];   // [dd][n] bf16, n xor-swizzled by dd
  const int type = blockIdx.z >> 2, ns = blockIdx.z & 3;
  const int bh = blockIdx.y, b = bh >> 4, h = bh & 15;
  const int kk0 = blockIdx.x * 64;
  const float* W = (type ? Wf : We) + ((size_t)(h * 256 + kk0)) * 4096;
  const int col0 = (type ? 2048 : 1024) + h * 64;
  const int tid = threadIdx.x, wid = tid >> 6, lane = tid & 63;
  const int lo = lane & 15, hi = lane >> 4;
  const int nbeg = ns << 10;

  // staging roles
  const int r = tid >> 2, c8 = (tid & 3) * 8;      // W: row r (kk), 8-col chunk
  const int n = tid >> 3, dd0 = (tid & 7) * 8;     // QKV: row n, 8-d chunk
  const float* Wrow = W + (size_t)r * 4096 + nbeg + c8;
  const u16* Qrow = QKV + (size_t)(b * 4096 + nbeg + n) * 3072 + col0 + dd0;
  const int wslot = r * 64 + ((c8 * 2) ^ ((r & 3) << 4));   // LDS byte offset
  const int rr = wid * 16 + lo;
  const int raoff = rr * 64 + ((hi * 16) ^ ((rr & 3) << 4));

  f32x4 acc[4] = {};
  f32x4 wA0, wA1, wB0, wB1;
  s16x8 qA, qB;

  // exactly 3 VMEM instructions per issue (2x dwordx4 + 1x dwordx4)
#define KISSUE(t, W0, W1, Q)                                        \
  { const float* wp_ = Wrow + (size_t)(t) * 32;                     \
    W0 = *(const f32x4*)wp_;                                        \
    W1 = *(const f32x4*)(wp_ + 4);                                  \
    Q = *(const s16x8*)(Qrow + (size_t)(t) * 32 * 3072); }

#define KSTAGE(bf_, W0, W1, Q)                                      \
  { s16x8 wv;                                                       \
    wv[0] = (short)f2bf(W0[0]); wv[1] = (short)f2bf(W0[1]);         \
    wv[2] = (short)f2bf(W0[2]); wv[3] = (short)f2bf(W0[3]);         \
    wv[4] = (short)f2bf(W1[0]); wv[5] = (short)f2bf(W1[1]);         \
    wv[6] = (short)f2bf(W1[2]); wv[7] = (short)f2bf(W1[3]);         \
    *(s16x8*)((char*)Wa[bf_] + wslot) = wv;                         \
    _Pragma("unroll")                                               \
    for (int q = 0; q < 8; ++q) {                                   \
      int dd = dd0 + q;                                             \
      Vt[bf_][dd * 32 + (n ^ (((dd >> 3) & 3) << 3))] = (u16)Q[q];  \
    } }

#define KCOMPUTE(bf_)                                               \
  { s16x8 a = *(const s16x8*)((const char*)Wa[bf_] + raoff);        \
    _Pragma("unroll")                                               \
    for (int dt = 0; dt < 4; ++dt) {                                \
      int dd = dt * 16 + lo;                                        \
      s16x8 bv = *(const s16x8*)&Vt[bf_][dd * 32 + ((hi * 8) ^ (((dd >> 3) & 3) << 3))]; \
      acc[dt] = __builtin_amdgcn_mfma_f32_16x16x32_bf16(a, bv, acc[dt], 0, 0, 0); \
    } }

  KISSUE(0, wA0, wA1, qA);
  KISSUE(1, wB0, wB1, qB);
#pragma unroll 1
  for (int tp = 0; tp < 15; ++tp) {
    asm volatile("s_waitcnt vmcnt(3)" ::: "memory");   // set A landed
    KSTAGE(0, wA0, wA1, qA);
    __syncthreads();
    KISSUE(2 * tp + 2, wA0, wA1, qA);
    KCOMPUTE(0);
    asm volatile("s_waitcnt vmcnt(3)" ::: "memory");   // set B landed
    KSTAGE(1, wB0, wB1, qB);
    __syncthreads();
    KISSUE(2 * tp + 3, wB0, wB1, qB);
    KCOMPUTE(1);
  }
  // tail: t=30 (buf0), t=31 (buf1), no further issues
  asm volatile("s_waitcnt vmcnt(3)" ::: "memory");
  KSTAGE(0, wA0, wA1, qA);
  __syncthreads();
  KCOMPUTE(0);
  asm volatile("s_waitcnt vmcnt(0)" ::: "memory");
  KSTAGE(1, wB0, wB1, qB);
  __syncthreads();
  KCOMPUTE(1);
#undef KISSUE
#undef KSTAGE
#undef KCOMPUTE

  const size_t pbase = ((size_t)((type * 32 + bh) * 4 + blockIdx.x) * 4 + ns) * 4096;
#pragma unroll
  for (int dt = 0; dt < 4; ++dt)
#pragma unroll
    for (int rg = 0; rg < 4; ++rg) {
      int kkl = wid * 16 + hi * 4 + rg;
      int dd = dt * 16 + lo;
      part[pbase + kkl * 64 + dd] = acc[dt][rg];
    }
}

// ---------- reduce 4 n-splits, add bias, write KeT (type0) / Vf (type1) ----------
__global__ __launch_bounds__(256) void kevf_reduce(
    const float* __restrict__ part, const float* __restrict__ bE,
    const float* __restrict__ bF, u16* __restrict__ KeT, u16* __restrict__ Vf) {
  const int tb = blockIdx.x;
  const int type = tb >> 7, bh = (tb >> 2) & 31, kc = tb & 3;
  const int t = threadIdx.x;
  const int kkl = t >> 2, dd0 = (t & 3) * 16;
  const float* p = part + (size_t)tb * 16384 + kkl * 64 + dd0;
  f32x4 s[4];
#pragma unroll
  for (int j = 0; j < 4; ++j) s[j] = ((const f32x4*)p)[j];
#pragma unroll
  for (int ns = 1; ns < 4; ++ns)
#pragma unroll
    for (int j = 0; j < 4; ++j) {
      f32x4 v = ((const f32x4*)(p + ns * 4096))[j];
      s[j][0] += v[0]; s[j][1] += v[1]; s[j][2] += v[2]; s[j][3] += v[3];
    }
  const int kk = kc * 64 + kkl;
  const float bias = (type ? bF : bE)[(bh & 15) * 256 + kk];
  if (type == 0) {
    u16* o = KeT + ((size_t)bh * 256 + kk) * 64 + dd0;
#pragma unroll
    for (int j = 0; j < 4; ++j) {
      u16x4 w = { f2bf(s[j][0] + bias), f2bf(s[j][1] + bias),
                  f2bf(s[j][2] + bias), f2bf(s[j][3] + bias) };
      *(u16x4*)(o + j * 4) = w;
    }
  } else {
#pragma unroll
    for (int j = 0; j < 4; ++j)
#pragma unroll
      for (int e = 0; e < 4; ++e) {
        int dd = dd0 + j * 4 + e;
        Vf[((size_t)bh * 64 + dd) * 256 + kk] = f2bf(s[j][e] + bias);
      }
  }
}

// ---------- fused attention: scores -> softmax -> PV -> gelu ----------
__global__ __launch_bounds__(256) void attn_fused(
    const u16* __restrict__ QKV, const u16* __restrict__ KeT,
    const u16* __restrict__ Vf, u16* __restrict__ attn) {
  __shared__ char smem[65536];
  char* sKe = smem;           // [256][128B] swizzled (aliased by P later)
  char* sVf = smem + 32768;   // [64][512B] swizzled
  const int tid = threadIdx.x, wid = tid >> 6, lane = tid & 63;
  const int lo = lane & 15, hi = lane >> 4;
  const int bh = blockIdx.y, b = bh >> 4, h = bh & 15;
  const int n0 = blockIdx.x * 64;

  const char* keg = (const char*)(KeT + (size_t)bh * 256 * 64);
  const char* vfg = (const char*)(Vf + (size_t)bh * 64 * 256);
#pragma unroll
  for (int i = 0; i < 8; ++i) {
    int ob = wid * 8192 + i * 1024;
    int o = ob + lane * 16;
    int kr = o >> 7, kc = o & 127;
    gload_lds16(keg + kr * 128 + (kc ^ ((kr & 7) << 4)), sKe + ob);
    int vr = o >> 9, vc = o & 511;
    gload_lds16(vfg + vr * 512 + (vc ^ ((vr & 7) << 4)), sVf + ob);
  }
  const u16* qp = QKV + (size_t)(b * 4096 + n0 + wid * 16 + lo) * 3072 + h * 64;
  s16x8 qf0 = *(const s16x8*)(qp + hi * 8);
  s16x8 qf1 = *(const s16x8*)(qp + 32 + hi * 8);
  __syncthreads();

  f32x4 sc[16];
#pragma unroll
  for (int nt = 0; nt < 16; ++nt) {
    int kk = nt * 16 + lo;
    int sw = (kk & 7) << 4;
    s16x8 b0 = *(const s16x8*)(sKe + kk * 128 + ((hi * 16) ^ sw));
    s16x8 b1 = *(const s16x8*)(sKe + kk * 128 + ((64 + hi * 16) ^ sw));
    f32x4 c = {0.f, 0.f, 0.f, 0.f};
    c = __builtin_amdgcn_mfma_f32_16x16x32_bf16(qf0, b0, c, 0, 0, 0);
    c = __builtin_amdgcn_mfma_f32_16x16x32_bf16(qf1, b1, c, 0, 0, 0);
    sc[nt] = c;
  }
  float mx[4], inv[4];
#pragma unroll
  for (int r = 0; r < 4; ++r) {
    float m = sc[0][r];
#pragma unroll
    for (int nt = 1; nt < 16; ++nt) m = fmaxf(m, sc[nt][r]);
    m = fmaxf(m, __shfl_xor(m, 1));
    m = fmaxf(m, __shfl_xor(m, 2));
    m = fmaxf(m, __shfl_xor(m, 4));
    m = fmaxf(m, __shfl_xor(m, 8));
    mx[r] = m;
  }
  const float SCL = 0.125f * 1.4426950408889634f;   // (1/sqrt(64)) * log2(e)
  float sm[4] = {0.f, 0.f, 0.f, 0.f};
#pragma unroll
  for (int nt = 0; nt < 16; ++nt)
#pragma unroll
    for (int r = 0; r < 4; ++r) {
      float p = exp2f((sc[nt][r] - mx[r]) * SCL);
      sc[nt][r] = p;
      sm[r] += p;
    }
#pragma unroll
  for (int r = 0; r < 4; ++r) {
    float s = sm[r];
    s += __shfl_xor(s, 1);
    s += __shfl_xor(s, 2);
    s += __shfl_xor(s, 4);
    s += __shfl_xor(s, 8);
    inv[r] = 1.0f / s;
  }
  __syncthreads();            // all waves done reading sKe
  char* pb = smem + wid * 8192;  // P aliases sKe region: [16 rows][512B] per wave
#pragma unroll
  for (int nt = 0; nt < 16; ++nt)
#pragma unroll
    for (int r = 0; r < 4; ++r) {
      int row = hi * 4 + r;
      int kk = nt * 16 + lo;
      *(u16*)(pb + row * 512 + ((kk * 2) ^ ((row & 7) << 4))) = f2bf(sc[nt][r] * inv[r]);
    }
  __syncthreads();
  s16x8 pa[8];
#pragma unroll
  for (int ks = 0; ks < 8; ++ks)
    pa[ks] = *(const s16x8*)(pb + lo * 512 + ((ks * 64 + hi * 16) ^ ((lo & 7) << 4)));
#pragma unroll
  for (int dt = 0; dt < 4; ++dt) {
    int dd = dt * 16 + lo;
    int sw = (dd & 7) << 4;
    f32x4 o = {0.f, 0.f, 0.f, 0.f};
#pragma unroll
    for (int ks = 0; ks < 8; ++ks) {
      s16x8 vb = *(const s16x8*)(sVf + dd * 512 + ((ks * 64 + hi * 16) ^ sw));
      o = __builtin_amdgcn_mfma_f32_16x16x32_bf16(pa[ks], vb, o, 0, 0, 0);
    }
#pragma unroll
    for (int r = 0; r < 4; ++r) {
      int row = n0 + wid * 16 + hi * 4 + r;
      float x = o[r];
      float g = 0.5f * x * (1.0f + erff(x * 0.7071067811865476f));
      attn[(size_t)(b * 4096 + row) * 1024 + h * 64 + dd] = f2bf(g);
    }
  }
}

// ---------- launcher ----------
extern "C" void kernel_launch(void* const* d_in, const int* in_sizes, int n_in,
                              void* d_out, int out_size, void* d_ws, size_t ws_size,
                              hipStream_t stream) {
  const float* x  = (const float*)d_in[0];
  const float* Wq = (const float*)d_in[1];
  const float* Wk = (const float*)d_in[2];
  const float* Wv = (const float*)d_in[3];
  const float* We = (const float*)d_in[4];
  const float* bE = (const float*)d_in[5];
  const float* Wf = (const float*)d_in[6];
  const float* bF = (const float*)d_in[7];
  const float* Wo = (const float*)d_in[8];
  const float* bo = (const float*)d_in[9];
  float* out = (float*)d_out;

  char* ws = (char*)d_ws;
  u16* xb   = (u16*)(ws);                 // 16,777,216 B  [8192][1024] bf16
  u16* Wqkv = (u16*)(ws + 16777216);      //  6,291,456 B  [3072][1024] bf16
  u16* Wob  = (u16*)(ws + 23068672);      //  2,097,152 B  [1024][1024] bf16
  u16* QKV  = (u16*)(ws + 25165824);      // 50,331,648 B  [8192][3072] bf16
  u16* KeT  = (u16*)(ws + 75497472);      //  1,048,576 B  [32][256][64] bf16
  u16* Vf   = (u16*)(ws + 76546048);      //  1,048,576 B  [32][64][256] bf16
  u16* attn = (u16*)(ws + 77594624);      // 16,777,216 B  [8192][1024] bf16
  float* part = (float*)(ws);             // 16,777,216 B  aliases xb (dead after QKV GEMM)

  cast_f32_bf16<<<8192, 256, 0, stream>>>(x, xb, 2097152);
  cast_f32_bf16<<<1024, 256, 0, stream>>>(Wq, Wqkv, 262144);
  cast_f32_bf16<<<1024, 256, 0, stream>>>(Wk, Wqkv + 1048576, 262144);
  cast_f32_bf16<<<1024, 256, 0, stream>>>(Wv, Wqkv + 2097152, 262144);
  cast_f32_bf16<<<1024, 256, 0, stream>>>(Wo, Wob, 262144);

  // QKV projection: [8192,3072] = x[8192,1024] @ Wqkv[3072,1024]^T
  gemm_pipe<0><<<dim3(12, 64), 512, 0, stream>>>(xb, Wqkv, QKV, nullptr,
                                                 1024, 1024, 1024, 3072);
  // Ke/Vf low-rank projections: 4-way n-split partials + reduce
  kevf_kernel<<<dim3(4, 32, 8), 256, 0, stream>>>(We, Wf, QKV, part);
  kevf_reduce<<<256, 256, 0, stream>>>(part, bE, bF, KeT, Vf);
  // fused scores/softmax/PV/gelu
  attn_fused<<<dim3(64, 32), 256, 0, stream>>>(QKV, KeT, Vf, attn);
  // output projection + bias
  gemm_pipe<1><<<dim3(4, 64), 512, 0, stream>>>(attn, Wob, out, bo,
                                                1024, 1024, 1024, 1024);
}

// Round 8
// 203.862 us; speedup vs baseline: 1.5544x; 1.0614x over previous
//
#include <hip/hip_runtime.h>

// ---------- types & helpers ----------
typedef unsigned short u16;
typedef float f32x4 __attribute__((ext_vector_type(4)));
typedef short s16x8 __attribute__((ext_vector_type(8)));
typedef unsigned short u16x4 __attribute__((ext_vector_type(4)));

__device__ __forceinline__ u16 f2bf(float f) {
  union { float f; unsigned u; } v; v.f = f;
  unsigned r = v.u + 0x7FFFu + ((v.u >> 16) & 1u);   // RNE
  return (u16)(r >> 16);
}

__device__ __forceinline__ void gload_lds16(const void* g, void* l) {
  __builtin_amdgcn_global_load_lds(
      (const __attribute__((address_space(1))) void*)g,
      (__attribute__((address_space(3))) void*)l, 16, 0, 0);
}

// ---------- fp32 -> bf16 cast ----------
__global__ __launch_bounds__(256) void cast_f32_bf16(
    const float* __restrict__ src, u16* __restrict__ dst, int n4) {
  int i = blockIdx.x * 256 + threadIdx.x;
  if (i >= n4) return;
  f32x4 v = ((const f32x4*)src)[i];
  u16x4 o = { f2bf(v[0]), f2bf(v[1]), f2bf(v[2]), f2bf(v[3]) };
  ((u16x4*)dst)[i] = o;
}

// ---------- pipelined bt-GEMM: C[M,N] = A[M,K] * B[N,K]^T ----------
// BM=BN=128, BK=32, 256 threads = 4 waves (2x2), per-wave 64x64.
// Depth-3 LDS pipeline (48 KiB -> 3 blocks/CU), counted vmcnt(4),
// XOR swizzle: slot bits [5:4] ^= addr bits [8:7]  (involution; conflict-free
// frag reads: bank-group = (lo0, hi0^lo1, hi1^lo2) is a bijection).
// FINAL=0: bf16 C, no bias.  FINAL=1: fp32 C + bias[col].
template <int FINAL>
__global__ __launch_bounds__(256) void gemm_pipe(
    const u16* __restrict__ A, const u16* __restrict__ B,
    void* __restrict__ Cout, const float* __restrict__ bias,
    int K, int lda, int ldb, int ldc) {
  __shared__ char smem[3 * 16384];   // slot s: A at s*16384, B at s*16384+8192
  const int tid = threadIdx.x;
  const int wid = tid >> 6, lane = tid & 63;
  const int lo = lane & 15, hi = lane >> 4;
  const int wr = wid >> 1, wc = wid & 1;
  const long brow = (long)blockIdx.y * 128;
  const long bcol = (long)blockIdx.x * 128;
  const int T = K >> 5;

  f32x4 acc[4][4] = {};

  const char* Ab = (const char*)(A + (size_t)brow * lda);
  const char* Bb = (const char*)(B + (size_t)bcol * ldb);
  const size_t ldab = (size_t)lda * 2, ldbb = (size_t)ldb * 2;

  // staging: wave w covers rows [32w, 32w+32) of the 128-row tile, two 1-KiB
  // chunks. LDS dest is linear; global source column is inverse-swizzled:
  // LDS[L] = G[L>>6][(L&63) ^ (((L>>7)&3)<<4)].
  const int La0 = wid * 2048 + lane * 16;
  const int La1 = La0 + 1024;
  const int ar0 = La0 >> 6, ac0 = (La0 & 63) ^ (((La0 >> 7) & 3) << 4);
  const int ar1 = La1 >> 6, ac1 = (La1 & 63) ^ (((La1 >> 7) & 3) << 4);
  const char* asrc0 = Ab + (size_t)ar0 * ldab + ac0;
  const char* asrc1 = Ab + (size_t)ar1 * ldab + ac1;
  const char* bsrc0 = Bb + (size_t)ar0 * ldbb + ac0;
  const char* bsrc1 = Bb + (size_t)ar1 * ldbb + ac1;

  // frag read byte-offsets: row*64 + ((hi ^ ((row>>1)&3))<<4)
  int ra[4], rb[4];
#pragma unroll
  for (int m = 0; m < 4; ++m) {
    int row = wr * 64 + m * 16 + lo;
    ra[m] = row * 64 + ((hi ^ ((row >> 1) & 3)) << 4);
  }
#pragma unroll
  for (int n = 0; n < 4; ++n) {
    int row = wc * 64 + n * 16 + lo;
    rb[n] = 8192 + row * 64 + ((hi ^ ((row >> 1) & 3)) << 4);
  }

#define STAGE(t)                                                    \
  {                                                                 \
    char* ls_ = smem + ((t) % 3) * 16384;                           \
    size_t kb_ = (size_t)(t) << 6;                                  \
    gload_lds16(asrc0 + kb_, ls_ + La0);                            \
    gload_lds16(asrc1 + kb_, ls_ + La1);                            \
    gload_lds16(bsrc0 + kb_, ls_ + 8192 + La0);                     \
    gload_lds16(bsrc1 + kb_, ls_ + 8192 + La1);                     \
  }

  // prologue: tiles 0,1 in flight (8 loads); wait tile 0 (4 oldest)
  STAGE(0); STAGE(1);
  asm volatile("s_waitcnt vmcnt(4)" ::: "memory");
  __builtin_amdgcn_s_barrier();
  __builtin_amdgcn_sched_barrier(0);

  for (int t = 0; t < T; ++t) {
    const char* buf = smem + (t % 3) * 16384;
    s16x8 af[4], bf[4];
#pragma unroll
    for (int m = 0; m < 4; ++m) af[m] = *(const s16x8*)(buf + ra[m]);
#pragma unroll
    for (int n = 0; n < 4; ++n) bf[n] = *(const s16x8*)(buf + rb[n]);
    if (t + 2 < T) STAGE(t + 2);   // slot (t+2)%3 == (t-1)%3: freed by last barrier
    __builtin_amdgcn_s_setprio(1);
#pragma unroll
    for (int m = 0; m < 4; ++m)
#pragma unroll
      for (int n = 0; n < 4; ++n)
        acc[m][n] = __builtin_amdgcn_mfma_f32_16x16x32_bf16(af[m], bf[n], acc[m][n], 0, 0, 0);
    __builtin_amdgcn_s_setprio(0);
    // tile t+1 must land before next iter; keep tile t+2's 4 loads in flight
    if (t + 2 < T) asm volatile("s_waitcnt vmcnt(4)" ::: "memory");
    else           asm volatile("s_waitcnt vmcnt(0)" ::: "memory");
    __builtin_amdgcn_s_barrier();
    __builtin_amdgcn_sched_barrier(0);
  }
#undef STAGE

#pragma unroll
  for (int m = 0; m < 4; ++m) {
#pragma unroll
    for (int n = 0; n < 4; ++n) {
#pragma unroll
      for (int r = 0; r < 4; ++r) {
        size_t row = brow + wr * 64 + m * 16 + hi * 4 + r;
        size_t col = bcol + wc * 64 + n * 16 + lo;
        float v = acc[m][n][r];
        if (FINAL) ((float*)Cout)[row * ldc + col] = v + bias[col];
        else       ((u16*)Cout)[row * ldc + col] = f2bf(v);
      }
    }
  }
}

// ---------- Ke/Vf partial: per (kc, bh, type*4+ns) block: 64k x 64d over 1024 n ----
// Reg-staged 2-deep pipeline, counted vmcnt, 1 barrier per 32-n step.
__global__ __launch_bounds__(256) void kevf_kernel(
    const float* __restrict__ We, const float* __restrict__ Wf,
    const u16* __restrict__ QKV, float* __restrict__ part) {
  __shared__ u16 Wa[2][64 * 32];   // [kk][n] bf16, xor-swizzled 16B slots
  __shared__ u16 Vt[2][64 * 32];   // [dd][n] bf16, n xor-swizzled by dd
  const int type = blockIdx.z >> 2, ns = blockIdx.z & 3;
  const int bh = blockIdx.y, b = bh >> 4, h = bh & 15;
  const int kk0 = blockIdx.x * 64;
  const float* W = (type ? Wf : We) + ((size_t)(h * 256 + kk0)) * 4096;
  const int col0 = (type ? 2048 : 1024) + h * 64;
  const int tid = threadIdx.x, wid = tid >> 6, lane = tid & 63;
  const int lo = lane & 15, hi = lane >> 4;
  const int nbeg = ns << 10;

  // staging roles
  const int r = tid >> 2, c8 = (tid & 3) * 8;      // W: row r (kk), 8-col chunk
  const int n = tid >> 3, dd0 = (tid & 7) * 8;     // QKV: row n, 8-d chunk
  const float* Wrow = W + (size_t)r * 4096 + nbeg + c8;
  const u16* Qrow = QKV + (size_t)(b * 4096 + nbeg + n) * 3072 + col0 + dd0;
  const int wslot = r * 64 + ((c8 * 2) ^ ((r & 3) << 4));   // LDS byte offset
  const int rr = wid * 16 + lo;
  const int raoff = rr * 64 + ((hi * 16) ^ ((rr & 3) << 4));

  f32x4 acc[4] = {};
  f32x4 wA0, wA1, wB0, wB1;
  s16x8 qA, qB;

  // exactly 3 VMEM instructions per issue (2x dwordx4 + 1x dwordx4)
#define KISSUE(t, W0, W1, Q)                                        \
  { const float* wp_ = Wrow + (size_t)(t) * 32;                     \
    W0 = *(const f32x4*)wp_;                                        \
    W1 = *(const f32x4*)(wp_ + 4);                                  \
    Q = *(const s16x8*)(Qrow + (size_t)(t) * 32 * 3072); }

#define KSTAGE(bf_, W0, W1, Q)                                      \
  { s16x8 wv;                                                       \
    wv[0] = (short)f2bf(W0[0]); wv[1] = (short)f2bf(W0[1]);         \
    wv[2] = (short)f2bf(W0[2]); wv[3] = (short)f2bf(W0[3]);         \
    wv[4] = (short)f2bf(W1[0]); wv[5] = (short)f2bf(W1[1]);         \
    wv[6] = (short)f2bf(W1[2]); wv[7] = (short)f2bf(W1[3]);         \
    *(s16x8*)((char*)Wa[bf_] + wslot) = wv;                         \
    _Pragma("unroll")                                               \
    for (int q = 0; q < 8; ++q) {                                   \
      int dd = dd0 + q;                                             \
      Vt[bf_][dd * 32 + (n ^ (((dd >> 3) & 3) << 3))] = (u16)Q[q];  \
    } }

#define KCOMPUTE(bf_)                                               \
  { s16x8 a = *(const s16x8*)((const char*)Wa[bf_] + raoff);        \
    _Pragma("unroll")                                               \
    for (int dt = 0; dt < 4; ++dt) {                                \
      int dd = dt * 16 + lo;                                        \
      s16x8 bv = *(const s16x8*)&Vt[bf_][dd * 32 + ((hi * 8) ^ (((dd >> 3) & 3) << 3))]; \
      acc[dt] = __builtin_amdgcn_mfma_f32_16x16x32_bf16(a, bv, acc[dt], 0, 0, 0); \
    } }

  KISSUE(0, wA0, wA1, qA);
  KISSUE(1, wB0, wB1, qB);
#pragma unroll 1
  for (int tp = 0; tp < 15; ++tp) {
    asm volatile("s_waitcnt vmcnt(3)" ::: "memory");   // set A landed
    KSTAGE(0, wA0, wA1, qA);
    __syncthreads();
    KISSUE(2 * tp + 2, wA0, wA1, qA);
    KCOMPUTE(0);
    asm volatile("s_waitcnt vmcnt(3)" ::: "memory");   // set B landed
    KSTAGE(1, wB0, wB1, qB);
    __syncthreads();
    KISSUE(2 * tp + 3, wB0, wB1, qB);
    KCOMPUTE(1);
  }
  // tail: t=30 (buf0), t=31 (buf1), no further issues
  asm volatile("s_waitcnt vmcnt(3)" ::: "memory");
  KSTAGE(0, wA0, wA1, qA);
  __syncthreads();
  KCOMPUTE(0);
  asm volatile("s_waitcnt vmcnt(0)" ::: "memory");
  KSTAGE(1, wB0, wB1, qB);
  __syncthreads();
  KCOMPUTE(1);
#undef KISSUE
#undef KSTAGE
#undef KCOMPUTE

  const size_t pbase = ((size_t)((type * 32 + bh) * 4 + blockIdx.x) * 4 + ns) * 4096;
#pragma unroll
  for (int dt = 0; dt < 4; ++dt)
#pragma unroll
    for (int rg = 0; rg < 4; ++rg) {
      int kkl = wid * 16 + hi * 4 + rg;
      int dd = dt * 16 + lo;
      part[pbase + kkl * 64 + dd] = acc[dt][rg];
    }
}

// ---------- reduce 4 n-splits, add bias, write KeT (type0) / Vf (type1) ----------
__global__ __launch_bounds__(256) void kevf_reduce(
    const float* __restrict__ part, const float* __restrict__ bE,
    const float* __restrict__ bF, u16* __restrict__ KeT, u16* __restrict__ Vf) {
  const int tb = blockIdx.x;
  const int type = tb >> 7, bh = (tb >> 2) & 31, kc = tb & 3;
  const int t = threadIdx.x;
  const int kkl = t >> 2, dd0 = (t & 3) * 16;
  const float* p = part + (size_t)tb * 16384 + kkl * 64 + dd0;
  f32x4 s[4];
#pragma unroll
  for (int j = 0; j < 4; ++j) s[j] = ((const f32x4*)p)[j];
#pragma unroll
  for (int ns = 1; ns < 4; ++ns)
#pragma unroll
    for (int j = 0; j < 4; ++j) {
      f32x4 v = ((const f32x4*)(p + ns * 4096))[j];
      s[j][0] += v[0]; s[j][1] += v[1]; s[j][2] += v[2]; s[j][3] += v[3];
    }
  const int kk = kc * 64 + kkl;
  const float bias = (type ? bF : bE)[(bh & 15) * 256 + kk];
  if (type == 0) {
    u16* o = KeT + ((size_t)bh * 256 + kk) * 64 + dd0;
#pragma unroll
    for (int j = 0; j < 4; ++j) {
      u16x4 w = { f2bf(s[j][0] + bias), f2bf(s[j][1] + bias),
                  f2bf(s[j][2] + bias), f2bf(s[j][3] + bias) };
      *(u16x4*)(o + j * 4) = w;
    }
  } else {
#pragma unroll
    for (int j = 0; j < 4; ++j)
#pragma unroll
      for (int e = 0; e < 4; ++e) {
        int dd = dd0 + j * 4 + e;
        Vf[((size_t)bh * 64 + dd) * 256 + kk] = f2bf(s[j][e] + bias);
      }
  }
}

// ---------- fused attention: scores -> softmax -> PV -> gelu ----------
__global__ __launch_bounds__(256) void attn_fused(
    const u16* __restrict__ QKV, const u16* __restrict__ KeT,
    const u16* __restrict__ Vf, u16* __restrict__ attn) {
  __shared__ char smem[65536];
  char* sKe = smem;           // [256][128B] swizzled (aliased by P later)
  char* sVf = smem + 32768;   // [64][512B] swizzled
  const int tid = threadIdx.x, wid = tid >> 6, lane = tid & 63;
  const int lo = lane & 15, hi = lane >> 4;
  const int bh = blockIdx.y, b = bh >> 4, h = bh & 15;
  const int n0 = blockIdx.x * 64;

  const char* keg = (const char*)(KeT + (size_t)bh * 256 * 64);
  const char* vfg = (const char*)(Vf + (size_t)bh * 64 * 256);
#pragma unroll
  for (int i = 0; i < 8; ++i) {
    int ob = wid * 8192 + i * 1024;
    int o = ob + lane * 16;
    int kr = o >> 7, kc = o & 127;
    gload_lds16(keg + kr * 128 + (kc ^ ((kr & 7) << 4)), sKe + ob);
    int vr = o >> 9, vc = o & 511;
    gload_lds16(vfg + vr * 512 + (vc ^ ((vr & 7) << 4)), sVf + ob);
  }
  const u16* qp = QKV + (size_t)(b * 4096 + n0 + wid * 16 + lo) * 3072 + h * 64;
  s16x8 qf0 = *(const s16x8*)(qp + hi * 8);
  s16x8 qf1 = *(const s16x8*)(qp + 32 + hi * 8);
  __syncthreads();

  f32x4 sc[16];
#pragma unroll
  for (int nt = 0; nt < 16; ++nt) {
    int kk = nt * 16 + lo;
    int sw = (kk & 7) << 4;
    s16x8 b0 = *(const s16x8*)(sKe + kk * 128 + ((hi * 16) ^ sw));
    s16x8 b1 = *(const s16x8*)(sKe + kk * 128 + ((64 + hi * 16) ^ sw));
    f32x4 c = {0.f, 0.f, 0.f, 0.f};
    c = __builtin_amdgcn_mfma_f32_16x16x32_bf16(qf0, b0, c, 0, 0, 0);
    c = __builtin_amdgcn_mfma_f32_16x16x32_bf16(qf1, b1, c, 0, 0, 0);
    sc[nt] = c;
  }
  float mx[4], inv[4];
#pragma unroll
  for (int r = 0; r < 4; ++r) {
    float m = sc[0][r];
#pragma unroll
    for (int nt = 1; nt < 16; ++nt) m = fmaxf(m, sc[nt][r]);
    m = fmaxf(m, __shfl_xor(m, 1));
    m = fmaxf(m, __shfl_xor(m, 2));
    m = fmaxf(m, __shfl_xor(m, 4));
    m = fmaxf(m, __shfl_xor(m, 8));
    mx[r] = m;
  }
  const float SCL = 0.125f * 1.4426950408889634f;   // (1/sqrt(64)) * log2(e)
  float sm[4] = {0.f, 0.f, 0.f, 0.f};
#pragma unroll
  for (int nt = 0; nt < 16; ++nt)
#pragma unroll
    for (int r = 0; r < 4; ++r) {
      float p = exp2f((sc[nt][r] - mx[r]) * SCL);
      sc[nt][r] = p;
      sm[r] += p;
    }
#pragma unroll
  for (int r = 0; r < 4; ++r) {
    float s = sm[r];
    s += __shfl_xor(s, 1);
    s += __shfl_xor(s, 2);
    s += __shfl_xor(s, 4);
    s += __shfl_xor(s, 8);
    inv[r] = 1.0f / s;
  }
  __syncthreads();            // all waves done reading sKe
  char* pb = smem + wid * 8192;  // P aliases sKe region: [16 rows][512B] per wave
#pragma unroll
  for (int nt = 0; nt < 16; ++nt)
#pragma unroll
    for (int r = 0; r < 4; ++r) {
      int row = hi * 4 + r;
      int kk = nt * 16 + lo;
      *(u16*)(pb + row * 512 + ((kk * 2) ^ ((row & 7) << 4))) = f2bf(sc[nt][r] * inv[r]);
    }
  __syncthreads();
  s16x8 pa[8];
#pragma unroll
  for (int ks = 0; ks < 8; ++ks)
    pa[ks] = *(const s16x8*)(pb + lo * 512 + ((ks * 64 + hi * 16) ^ ((lo & 7) << 4)));
#pragma unroll
  for (int dt = 0; dt < 4; ++dt) {
    int dd = dt * 16 + lo;
    int sw = (dd & 7) << 4;
    f32x4 o = {0.f, 0.f, 0.f, 0.f};
#pragma unroll
    for (int ks = 0; ks < 8; ++ks) {
      s16x8 vb = *(const s16x8*)(sVf + dd * 512 + ((ks * 64 + hi * 16) ^ sw));
      o = __builtin_amdgcn_mfma_f32_16x16x32_bf16(pa[ks], vb, o, 0, 0, 0);
    }
#pragma unroll
    for (int r = 0; r < 4; ++r) {
      int row = n0 + wid * 16 + hi * 4 + r;
      float x = o[r];
      float g = 0.5f * x * (1.0f + erff(x * 0.7071067811865476f));
      attn[(size_t)(b * 4096 + row) * 1024 + h * 64 + dd] = f2bf(g);
    }
  }
}

// ---------- launcher ----------
extern "C" void kernel_launch(void* const* d_in, const int* in_sizes, int n_in,
                              void* d_out, int out_size, void* d_ws, size_t ws_size,
                              hipStream_t stream) {
  const float* x  = (const float*)d_in[0];
  const float* Wq = (const float*)d_in[1];
  const float* Wk = (const float*)d_in[2];
  const float* Wv = (const float*)d_in[3];
  const float* We = (const float*)d_in[4];
  const float* bE = (const float*)d_in[5];
  const float* Wf = (const float*)d_in[6];
  const float* bF = (const float*)d_in[7];
  const float* Wo = (const float*)d_in[8];
  const float* bo = (const float*)d_in[9];
  float* out = (float*)d_out;

  char* ws = (char*)d_ws;
  u16* xb   = (u16*)(ws);                 // 16,777,216 B  [8192][1024] bf16
  u16* Wqkv = (u16*)(ws + 16777216);      //  6,291,456 B  [3072][1024] bf16
  u16* Wob  = (u16*)(ws + 23068672);      //  2,097,152 B  [1024][1024] bf16
  u16* QKV  = (u16*)(ws + 25165824);      // 50,331,648 B  [8192][3072] bf16
  u16* KeT  = (u16*)(ws + 75497472);      //  1,048,576 B  [32][256][64] bf16
  u16* Vf   = (u16*)(ws + 76546048);      //  1,048,576 B  [32][64][256] bf16
  u16* attn = (u16*)(ws + 77594624);      // 16,777,216 B  [8192][1024] bf16
  float* part = (float*)(ws);             // 16,777,216 B  aliases xb (dead after QKV GEMM)

  cast_f32_bf16<<<8192, 256, 0, stream>>>(x, xb, 2097152);
  cast_f32_bf16<<<1024, 256, 0, stream>>>(Wq, Wqkv, 262144);
  cast_f32_bf16<<<1024, 256, 0, stream>>>(Wk, Wqkv + 1048576, 262144);
  cast_f32_bf16<<<1024, 256, 0, stream>>>(Wv, Wqkv + 2097152, 262144);
  cast_f32_bf16<<<1024, 256, 0, stream>>>(Wo, Wob, 262144);

  // QKV projection: [8192,3072] = x[8192,1024] @ Wqkv[3072,1024]^T
  gemm_pipe<0><<<dim3(24, 64), 256, 0, stream>>>(xb, Wqkv, QKV, nullptr,
                                                 1024, 1024, 1024, 3072);
  // Ke/Vf low-rank projections: 4-way n-split partials + reduce
  kevf_kernel<<<dim3(4, 32, 8), 256, 0, stream>>>(We, Wf, QKV, part);
  kevf_reduce<<<256, 256, 0, stream>>>(part, bE, bF, KeT, Vf);
  // fused scores/softmax/PV/gelu
  attn_fused<<<dim3(64, 32), 256, 0, stream>>>(QKV, KeT, Vf, attn);
  // output projection + bias
  gemm_pipe<1><<<dim3(8, 64), 256, 0, stream>>>(attn, Wob, out, bo,
                                                1024, 1024, 1024, 1024);
}

// Round 11
// 200.626 us; speedup vs baseline: 1.5795x; 1.0161x over previous
//
#include <hip/hip_runtime.h>

// ---------- types & helpers ----------
typedef unsigned short u16;
typedef float f32x4 __attribute__((ext_vector_type(4)));
typedef short s16x8 __attribute__((ext_vector_type(8)));
typedef unsigned short u16x4 __attribute__((ext_vector_type(4)));

__device__ __forceinline__ u16 f2bf(float f) {
  union { float f; unsigned u; } v; v.f = f;
  unsigned r = v.u + 0x7FFFu + ((v.u >> 16) & 1u);   // RNE
  return (u16)(r >> 16);
}

__device__ __forceinline__ void gload_lds16(const void* g, void* l) {
  __builtin_amdgcn_global_load_lds(
      (const __attribute__((address_space(1))) void*)g,
      (__attribute__((address_space(3))) void*)l, 16, 0, 0);
}

// ---------- fp32 -> bf16 cast ----------
__global__ __launch_bounds__(256) void cast_f32_bf16(
    const float* __restrict__ src, u16* __restrict__ dst, int n4) {
  int i = blockIdx.x * 256 + threadIdx.x;
  if (i >= n4) return;
  f32x4 v = ((const f32x4*)src)[i];
  u16x4 o = { f2bf(v[0]), f2bf(v[1]), f2bf(v[2]), f2bf(v[3]) };
  ((u16x4*)dst)[i] = o;
}

// ---------- pipelined bt-GEMM: C[M,N] = A[M,K] * B[N,K]^T ----------
// BM=128, BN=256, BK=32, 256 threads = 4 waves (2x2), per-wave 64x128
// (acc[4][8], 32 MFMA / 12KB frag-reads -> halved LDS traffic per FLOP).
// Depth-3 LDS pipeline (72 KiB -> 2 blocks/CU), counted vmcnt(6),
// XOR swizzle: slot bits[5:4] ^= linear bits[8:7] (= (row>>1)&3; involution,
// conflict-free frag reads, verified 0-conflict in round 8).
// FINAL=0: bf16 C, no bias.  FINAL=1: fp32 C + bias[col].
template <int FINAL>
__global__ __launch_bounds__(256, 2) void gemm_pipe(
    const u16* __restrict__ A, const u16* __restrict__ B,
    void* __restrict__ Cout, const float* __restrict__ bias,
    int K, int lda, int ldb, int ldc) {
  __shared__ char smem[3 * 8192 + 3 * 16384];  // A slots [0,24K), B slots [24K,72K)
  const int tid = threadIdx.x;
  const int wid = tid >> 6, lane = tid & 63;
  const int lo = lane & 15, hi = lane >> 4;
  const int wr = wid >> 1, wc = wid & 1;
  const long brow = (long)blockIdx.y * 128;
  const long bcol = (long)blockIdx.x * 256;
  const int T = K >> 5;

  f32x4 acc[4][8] = {};

  const char* Ab = (const char*)(A + (size_t)brow * lda);
  const char* Bb = (const char*)(B + (size_t)bcol * ldb);
  const size_t ldab = (size_t)lda * 2, ldbb = (size_t)ldb * 2;

  // staging: A = 8KB (2 chunks/wave), B = 16KB (4 chunks/wave); LDS dest is
  // linear (wave base + lane*16); global source col is inverse-swizzled.
  const int LA0 = wid * 2048 + lane * 16, LA1 = LA0 + 1024;
  const int LB0 = wid * 4096 + lane * 16, LB1 = LB0 + 1024;
  const int LB2 = LB0 + 2048, LB3 = LB0 + 3072;
#define SRCCOL(L) (((L) & 63) ^ ((((L) >> 7) & 3) << 4))
  const char* aS0 = Ab + (size_t)(LA0 >> 6) * ldab + SRCCOL(LA0);
  const char* aS1 = Ab + (size_t)(LA1 >> 6) * ldab + SRCCOL(LA1);
  const char* bS0 = Bb + (size_t)(LB0 >> 6) * ldbb + SRCCOL(LB0);
  const char* bS1 = Bb + (size_t)(LB1 >> 6) * ldbb + SRCCOL(LB1);
  const char* bS2 = Bb + (size_t)(LB2 >> 6) * ldbb + SRCCOL(LB2);
  const char* bS3 = Bb + (size_t)(LB3 >> 6) * ldbb + SRCCOL(LB3);
#undef SRCCOL

  // frag read byte-offsets: row*64 + ((hi ^ ((row>>1)&3))<<4)
  int ra[4], rb[8];
#pragma unroll
  for (int m = 0; m < 4; ++m) {
    int row = wr * 64 + m * 16 + lo;
    ra[m] = row * 64 + ((hi ^ ((row >> 1) & 3)) << 4);
  }
#pragma unroll
  for (int n = 0; n < 8; ++n) {
    int row = wc * 128 + n * 16 + lo;
    rb[n] = row * 64 + ((hi ^ ((row >> 1) & 3)) << 4);
  }

#define STAGE(t)                                                    \
  {                                                                 \
    char* sa_ = smem + ((t) % 3) * 8192;                            \
    char* sb_ = smem + 24576 + ((t) % 3) * 16384;                   \
    size_t kb_ = (size_t)(t) << 6;                                  \
    gload_lds16(aS0 + kb_, sa_ + LA0);                              \
    gload_lds16(aS1 + kb_, sa_ + LA1);                              \
    gload_lds16(bS0 + kb_, sb_ + LB0);                              \
    gload_lds16(bS1 + kb_, sb_ + LB1);                              \
    gload_lds16(bS2 + kb_, sb_ + LB2);                              \
    gload_lds16(bS3 + kb_, sb_ + LB3);                              \
  }

  // prologue: tiles 0,1 in flight (12 loads); wait tile 0 (6 oldest)
  STAGE(0); STAGE(1);
  asm volatile("s_waitcnt vmcnt(6)" ::: "memory");
  __builtin_amdgcn_s_barrier();
  __builtin_amdgcn_sched_barrier(0);

  for (int t = 0; t < T; ++t) {
    const char* sa = smem + (t % 3) * 8192;
    const char* sb = smem + 24576 + (t % 3) * 16384;
    s16x8 af[4], bf[8];
#pragma unroll
    for (int m = 0; m < 4; ++m) af[m] = *(const s16x8*)(sa + ra[m]);
#pragma unroll
    for (int n = 0; n < 8; ++n) bf[n] = *(const s16x8*)(sb + rb[n]);
    if (t + 2 < T) STAGE(t + 2);   // slot (t+2)%3 == (t-1)%3: freed by last barrier
    __builtin_amdgcn_s_setprio(1);
#pragma unroll
    for (int m = 0; m < 4; ++m)
#pragma unroll
      for (int n = 0; n < 8; ++n)
        acc[m][n] = __builtin_amdgcn_mfma_f32_16x16x32_bf16(af[m], bf[n], acc[m][n], 0, 0, 0);
    __builtin_amdgcn_s_setprio(0);
    if (t + 2 < T) asm volatile("s_waitcnt vmcnt(6)" ::: "memory");
    else           asm volatile("s_waitcnt vmcnt(0)" ::: "memory");
    __builtin_amdgcn_s_barrier();
    __builtin_amdgcn_sched_barrier(0);
  }
#undef STAGE

#pragma unroll
  for (int m = 0; m < 4; ++m) {
#pragma unroll
    for (int n = 0; n < 8; ++n) {
#pragma unroll
      for (int r = 0; r < 4; ++r) {
        size_t row = brow + wr * 64 + m * 16 + hi * 4 + r;
        size_t col = bcol + wc * 128 + n * 16 + lo;
        float v = acc[m][n][r];
        if (FINAL) ((float*)Cout)[row * ldc + col] = v + bias[col];
        else       ((u16*)Cout)[row * ldc + col] = f2bf(v);
      }
    }
  }
}

// ---------- Ke/Vf partial: per (kc, bh, type*4+ns) block: 64k x 64d over 1024 n ----
// 64-n steps (16 total), depth-3 register rotation. W loaded DIRECTLY as
// A-frags (no LDS round-trip); only QKV transposed via LDS with two-level
// swizzle n ^= ((dd&7)^((dd>>4)&3))<<3.
// ORDER FIX (round-10 bug): w[t%3] must be consumed into a0/a1 BEFORE
// KISSUE(t+3) overwrites the same rotation slot.
__global__ __launch_bounds__(256) void kevf_kernel(
    const float* __restrict__ We, const float* __restrict__ Wf,
    const u16* __restrict__ QKV, float* __restrict__ part) {
  __shared__ u16 Vt[2][64 * 64];   // [buf][dd*64 + swizzled n], 2 x 8KB
  const int type = blockIdx.z >> 2, ns = blockIdx.z & 3;
  const int bh = blockIdx.y, b = bh >> 4, h = bh & 15;
  const int kk0 = blockIdx.x * 64;
  const float* W = (type ? Wf : We) + ((size_t)(h * 256 + kk0)) * 4096;
  const int col0 = (type ? 2048 : 1024) + h * 64;
  const int tid = threadIdx.x, wid = tid >> 6, lane = tid & 63;
  const int lo = lane & 15, hi = lane >> 4;
  const int nbeg = ns << 10;

  // A-frag source: lane owns W row rr, k-chunk hi (16 rows x 4 hi = full cover)
  const int rr = wid * 16 + lo;
  const float* wsrc = W + (size_t)rr * 4096 + nbeg + hi * 8;
  // QKV staging: thread owns row qn (0..63), 16-col chunk qc
  const int qn = tid >> 2, qc = (tid & 3) * 16;
  const u16* qsrc = QKV + ((size_t)b * 4096 + nbeg + qn) * 3072 + col0 + qc;

  f32x4 acc[4] = {};
  f32x4 w[3][4];
  s16x8 q[3][2];

#define KISSUE(t) {                                       \
    const float* wp_ = wsrc + (size_t)(t) * 64;           \
    w[(t) % 3][0] = *(const f32x4*)wp_;                   \
    w[(t) % 3][1] = *(const f32x4*)(wp_ + 4);             \
    w[(t) % 3][2] = *(const f32x4*)(wp_ + 32);            \
    w[(t) % 3][3] = *(const f32x4*)(wp_ + 36);            \
    const u16* qp_ = qsrc + (size_t)(t) * 64 * 3072;      \
    q[(t) % 3][0] = *(const s16x8*)qp_;                   \
    q[(t) % 3][1] = *(const s16x8*)(qp_ + 8); }

  KISSUE(0); KISSUE(1); KISSUE(2);
#pragma unroll
  for (int t = 0; t < 16; ++t) {
    u16* vb = Vt[t & 1];
    // transpose-stage QKV rows -> Vt[dd][n]  (consumes q[t%3])
#pragma unroll
    for (int e = 0; e < 16; ++e) {
      int dd = qc + e;
      int sw = (dd & 7) ^ ((dd >> 4) & 3);
      u16 val = (e < 8) ? (u16)q[t % 3][0][e] : (u16)q[t % 3][1][e - 8];
      vb[dd * 64 + (qn ^ (sw << 3))] = val;
    }
    // A-frags from registers (fp32 -> bf16) — consumes w[t%3] BEFORE re-issue
    s16x8 a0, a1;
#pragma unroll
    for (int j = 0; j < 4; ++j) {
      a0[j]     = (short)f2bf(w[t % 3][0][j]);
      a0[j + 4] = (short)f2bf(w[t % 3][1][j]);
      a1[j]     = (short)f2bf(w[t % 3][2][j]);
      a1[j + 4] = (short)f2bf(w[t % 3][3][j]);
    }
    if (t + 3 < 16) KISSUE(t + 3);   // rotation slot (t+3)%3 == t%3: now free
    __syncthreads();                  // Vt[t&1] visible to all waves
#pragma unroll
    for (int dt = 0; dt < 4; ++dt) {
      int dd = dt * 16 + lo;
      int sw = (lo & 7) ^ dt;
      s16x8 b0 = *(const s16x8*)&vb[dd * 64 + ((hi * 8) ^ (sw << 3))];
      s16x8 b1 = *(const s16x8*)&vb[dd * 64 + ((32 + hi * 8) ^ (sw << 3))];
      acc[dt] = __builtin_amdgcn_mfma_f32_16x16x32_bf16(a0, b0, acc[dt], 0, 0, 0);
      acc[dt] = __builtin_amdgcn_mfma_f32_16x16x32_bf16(a1, b1, acc[dt], 0, 0, 0);
    }
    // next write of Vt[t&1] is step t+2, after barrier(t+1): WAR-safe
    // (syncthreads drains lgkm; reg-destined global loads stay in flight)
  }
#undef KISSUE

  const size_t pbase = ((size_t)((type * 32 + bh) * 4 + blockIdx.x) * 4 + ns) * 4096;
#pragma unroll
  for (int dt = 0; dt < 4; ++dt)
#pragma unroll
    for (int rg = 0; rg < 4; ++rg) {
      int kkl = wid * 16 + hi * 4 + rg;
      int dd = dt * 16 + lo;
      part[pbase + kkl * 64 + dd] = acc[dt][rg];
    }
}

// ---------- reduce 4 n-splits, add bias, write KeT (type0) / Vf (type1) ----------
__global__ __launch_bounds__(256) void kevf_reduce(
    const float* __restrict__ part, const float* __restrict__ bE,
    const float* __restrict__ bF, u16* __restrict__ KeT, u16* __restrict__ Vf) {
  const int tb = blockIdx.x;
  const int type = tb >> 7, bh = (tb >> 2) & 31, kc = tb & 3;
  const int t = threadIdx.x;
  const int kkl = t >> 2, dd0 = (t & 3) * 16;
  const float* p = part + (size_t)tb * 16384 + kkl * 64 + dd0;
  f32x4 s[4];
#pragma unroll
  for (int j = 0; j < 4; ++j) s[j] = ((const f32x4*)p)[j];
#pragma unroll
  for (int ns = 1; ns < 4; ++ns)
#pragma unroll
    for (int j = 0; j < 4; ++j) {
      f32x4 v = ((const f32x4*)(p + ns * 4096))[j];
      s[j][0] += v[0]; s[j][1] += v[1]; s[j][2] += v[2]; s[j][3] += v[3];
    }
  const int kk = kc * 64 + kkl;
  const float bias = (type ? bF : bE)[(bh & 15) * 256 + kk];
  if (type == 0) {
    u16* o = KeT + ((size_t)bh * 256 + kk) * 64 + dd0;
#pragma unroll
    for (int j = 0; j < 4; ++j) {
      u16x4 w = { f2bf(s[j][0] + bias), f2bf(s[j][1] + bias),
                  f2bf(s[j][2] + bias), f2bf(s[j][3] + bias) };
      *(u16x4*)(o + j * 4) = w;
    }
  } else {
#pragma unroll
    for (int j = 0; j < 4; ++j)
#pragma unroll
      for (int e = 0; e < 4; ++e) {
        int dd = dd0 + j * 4 + e;
        Vf[((size_t)bh * 64 + dd) * 256 + kk] = f2bf(s[j][e] + bias);
      }
  }
}

// ---------- fused attention: scores -> softmax -> PV -> gelu ----------
__global__ __launch_bounds__(256) void attn_fused(
    const u16* __restrict__ QKV, const u16* __restrict__ KeT,
    const u16* __restrict__ Vf, u16* __restrict__ attn) {
  __shared__ char smem[65536];
  char* sKe = smem;           // [256][128B] swizzled (aliased by P later)
  char* sVf = smem + 32768;   // [64][512B] swizzled
  const int tid = threadIdx.x, wid = tid >> 6, lane = tid & 63;
  const int lo = lane & 15, hi = lane >> 4;
  const int bh = blockIdx.y, b = bh >> 4, h = bh & 15;
  const int n0 = blockIdx.x * 64;

  const char* keg = (const char*)(KeT + (size_t)bh * 256 * 64);
  const char* vfg = (const char*)(Vf + (size_t)bh * 64 * 256);
#pragma unroll
  for (int i = 0; i < 8; ++i) {
    int ob = wid * 8192 + i * 1024;
    int o = ob + lane * 16;
    int kr = o >> 7, kc = o & 127;
    gload_lds16(keg + kr * 128 + (kc ^ ((kr & 7) << 4)), sKe + ob);
    int vr = o >> 9, vc = o & 511;
    gload_lds16(vfg + vr * 512 + (vc ^ ((vr & 7) << 4)), sVf + ob);
  }
  const u16* qp = QKV + (size_t)(b * 4096 + n0 + wid * 16 + lo) * 3072 + h * 64;
  s16x8 qf0 = *(const s16x8*)(qp + hi * 8);
  s16x8 qf1 = *(const s16x8*)(qp + 32 + hi * 8);
  __syncthreads();

  f32x4 sc[16];
#pragma unroll
  for (int nt = 0; nt < 16; ++nt) {
    int kk = nt * 16 + lo;
    int sw = (kk & 7) << 4;
    s16x8 b0 = *(const s16x8*)(sKe + kk * 128 + ((hi * 16) ^ sw));
    s16x8 b1 = *(const s16x8*)(sKe + kk * 128 + ((64 + hi * 16) ^ sw));
    f32x4 c = {0.f, 0.f, 0.f, 0.f};
    c = __builtin_amdgcn_mfma_f32_16x16x32_bf16(qf0, b0, c, 0, 0, 0);
    c = __builtin_amdgcn_mfma_f32_16x16x32_bf16(qf1, b1, c, 0, 0, 0);
    sc[nt] = c;
  }
  float mx[4], inv[4];
#pragma unroll
  for (int r = 0; r < 4; ++r) {
    float m = sc[0][r];
#pragma unroll
    for (int nt = 1; nt < 16; ++nt) m = fmaxf(m, sc[nt][r]);
    m = fmaxf(m, __shfl_xor(m, 1));
    m = fmaxf(m, __shfl_xor(m, 2));
    m = fmaxf(m, __shfl_xor(m, 4));
    m = fmaxf(m, __shfl_xor(m, 8));
    mx[r] = m;
  }
  const float SCL = 0.125f * 1.4426950408889634f;   // (1/sqrt(64)) * log2(e)
  float sm[4] = {0.f, 0.f, 0.f, 0.f};
#pragma unroll
  for (int nt = 0; nt < 16; ++nt)
#pragma unroll
    for (int r = 0; r < 4; ++r) {
      float p = exp2f((sc[nt][r] - mx[r]) * SCL);
      sc[nt][r] = p;
      sm[r] += p;
    }
#pragma unroll
  for (int r = 0; r < 4; ++r) {
    float s = sm[r];
    s += __shfl_xor(s, 1);
    s += __shfl_xor(s, 2);
    s += __shfl_xor(s, 4);
    s += __shfl_xor(s, 8);
    inv[r] = 1.0f / s;
  }
  __syncthreads();            // all waves done reading sKe
  char* pb = smem + wid * 8192;  // P aliases sKe region: [16 rows][512B] per wave
#pragma unroll
  for (int nt = 0; nt < 16; ++nt)
#pragma unroll
    for (int r = 0; r < 4; ++r) {
      int row = hi * 4 + r;
      int kk = nt * 16 + lo;
      *(u16*)(pb + row * 512 + ((kk * 2) ^ ((row & 7) << 4))) = f2bf(sc[nt][r] * inv[r]);
    }
  __syncthreads();
  s16x8 pa[8];
#pragma unroll
  for (int ks = 0; ks < 8; ++ks)
    pa[ks] = *(const s16x8*)(pb + lo * 512 + ((ks * 64 + hi * 16) ^ ((lo & 7) << 4)));
#pragma unroll
  for (int dt = 0; dt < 4; ++dt) {
    int dd = dt * 16 + lo;
    int sw = (dd & 7) << 4;
    f32x4 o = {0.f, 0.f, 0.f, 0.f};
#pragma unroll
    for (int ks = 0; ks < 8; ++ks) {
      s16x8 vb = *(const s16x8*)(sVf + dd * 512 + ((ks * 64 + hi * 16) ^ sw));
      o = __builtin_amdgcn_mfma_f32_16x16x32_bf16(pa[ks], vb, o, 0, 0, 0);
    }
#pragma unroll
    for (int r = 0; r < 4; ++r) {
      int row = n0 + wid * 16 + hi * 4 + r;
      float x = o[r];
      float g = 0.5f * x * (1.0f + erff(x * 0.7071067811865476f));
      attn[(size_t)(b * 4096 + row) * 1024 + h * 64 + dd] = f2bf(g);
    }
  }
}

// ---------- launcher ----------
extern "C" void kernel_launch(void* const* d_in, const int* in_sizes, int n_in,
                              void* d_out, int out_size, void* d_ws, size_t ws_size,
                              hipStream_t stream) {
  const float* x  = (const float*)d_in[0];
  const float* Wq = (const float*)d_in[1];
  const float* Wk = (const float*)d_in[2];
  const float* Wv = (const float*)d_in[3];
  const float* We = (const float*)d_in[4];
  const float* bE = (const float*)d_in[5];
  const float* Wf = (const float*)d_in[6];
  const float* bF = (const float*)d_in[7];
  const float* Wo = (const float*)d_in[8];
  const float* bo = (const float*)d_in[9];
  float* out = (float*)d_out;

  char* ws = (char*)d_ws;
  u16* xb   = (u16*)(ws);                 // 16,777,216 B  [8192][1024] bf16
  u16* Wqkv = (u16*)(ws + 16777216);      //  6,291,456 B  [3072][1024] bf16
  u16* Wob  = (u16*)(ws + 23068672);      //  2,097,152 B  [1024][1024] bf16
  u16* QKV  = (u16*)(ws + 25165824);      // 50,331,648 B  [8192][3072] bf16
  u16* KeT  = (u16*)(ws + 75497472);      //  1,048,576 B  [32][256][64] bf16
  u16* Vf   = (u16*)(ws + 76546048);      //  1,048,576 B  [32][64][256] bf16
  u16* attn = (u16*)(ws + 77594624);      // 16,777,216 B  [8192][1024] bf16
  float* part = (float*)(ws);             // 16,777,216 B  aliases xb (dead after QKV GEMM)

  cast_f32_bf16<<<8192, 256, 0, stream>>>(x, xb, 2097152);
  cast_f32_bf16<<<1024, 256, 0, stream>>>(Wq, Wqkv, 262144);
  cast_f32_bf16<<<1024, 256, 0, stream>>>(Wk, Wqkv + 1048576, 262144);
  cast_f32_bf16<<<1024, 256, 0, stream>>>(Wv, Wqkv + 2097152, 262144);
  cast_f32_bf16<<<1024, 256, 0, stream>>>(Wo, Wob, 262144);

  // QKV projection: [8192,3072] = x[8192,1024] @ Wqkv[3072,1024]^T
  gemm_pipe<0><<<dim3(12, 64), 256, 0, stream>>>(xb, Wqkv, QKV, nullptr,
                                                 1024, 1024, 1024, 3072);
  // Ke/Vf low-rank projections: 4-way n-split partials + reduce
  kevf_kernel<<<dim3(4, 32, 8), 256, 0, stream>>>(We, Wf, QKV, part);
  kevf_reduce<<<256, 256, 0, stream>>>(part, bE, bF, KeT, Vf);
  // fused scores/softmax/PV/gelu
  attn_fused<<<dim3(64, 32), 256, 0, stream>>>(QKV, KeT, Vf, attn);
  // output projection + bias
  gemm_pipe<1><<<dim3(4, 64), 256, 0, stream>>>(attn, Wob, out, bo,
                                                1024, 1024, 1024, 1024);
}